// Round 17
// baseline (162.748 us; speedup 1.0000x reference)
//
#include <hip/hip_runtime.h>
#include <cmath>

// ---------------------------------------------------------------------------
// T5 MHSA: x->(QKV proj, f16 MFMA GEMM) -> flash attn w/ T5 bias -> out proj
// All matmuls on MFMA. fp16 intermediates, fp32 accum.
// ---------------------------------------------------------------------------

typedef _Float16 f16x8 __attribute__((ext_vector_type(8)));
typedef _Float16 f16x4 __attribute__((ext_vector_type(4)));
typedef float    f32x4 __attribute__((ext_vector_type(4)));

#define NEG_INF (-__builtin_inff())
#define LOG2E 1.4426950408889634f

#if __has_builtin(__builtin_amdgcn_exp2f)
#define EXP2(x) __builtin_amdgcn_exp2f(x)
#else
#define EXP2(x) exp2f(x)
#endif

__device__ __forceinline__ void gl_lds16(const void* g, void* l) {
  __builtin_amdgcn_global_load_lds(
      (__attribute__((address_space(1))) void*)g,
      (__attribute__((address_space(3))) void*)l,
      16, 0, 0);
}

__device__ __forceinline__ f32x4 mfma32(f16x8 a, f16x8 b, f32x4 c) {
  return __builtin_amdgcn_mfma_f32_16x16x32_f16(a, b, c, 0, 0, 0);
}
__device__ __forceinline__ f32x4 mfma16(f16x4 a, f16x4 b, f32x4 c) {
  return __builtin_amdgcn_mfma_f32_16x16x16f16(a, b, c, 0, 0, 0);
}

typedef __attribute__((address_space(3))) _Float16* lds_f16p;

#define DSR(d, a, o) \
  asm volatile("ds_read_b128 %0, %1 offset:" o : "=v"(d) : "v"(a))

#define GEMM_VM4 asm volatile("s_waitcnt vmcnt(4)" ::: "memory")
#define GEMM_VM3 asm volatile("s_waitcnt vmcnt(3)" ::: "memory")
#define GEMM_VM0 asm volatile("s_waitcnt vmcnt(0)" ::: "memory")
#define GEMM_BAR __builtin_amdgcn_s_barrier()

// shared inner compute: 8 asm ds_read_b128 + lgkm ladder + 16 MFMA
#define GEMM_COMPUTE(aB, bB)                             \
  do {                                                   \
    f16x8 af0, af1, af2, af3, bf0, bf1, bf2, bf3;        \
    DSR(af0, aB, "0");                                   \
    DSR(bf0, bB, "0");                                   \
    DSR(af1, aB, "1024");                                \
    DSR(bf1, bB, "1024");                                \
    DSR(af2, aB, "2048");                                \
    DSR(bf2, bB, "2048");                                \
    DSR(af3, aB, "3072");                                \
    DSR(bf3, bB, "3072");                                \
    asm volatile("s_waitcnt lgkmcnt(4)" ::: "memory");   \
    __builtin_amdgcn_sched_barrier(0);                   \
    __builtin_amdgcn_s_setprio(1);                       \
    acc[0][0] = mfma32(af0, bf0, acc[0][0]);             \
    acc[0][1] = mfma32(af0, bf1, acc[0][1]);             \
    acc[1][0] = mfma32(af1, bf0, acc[1][0]);             \
    acc[1][1] = mfma32(af1, bf1, acc[1][1]);             \
    asm volatile("s_waitcnt lgkmcnt(0)" ::: "memory");   \
    __builtin_amdgcn_sched_barrier(0);                   \
    acc[0][2] = mfma32(af0, bf2, acc[0][2]);             \
    acc[0][3] = mfma32(af0, bf3, acc[0][3]);             \
    acc[1][2] = mfma32(af1, bf2, acc[1][2]);             \
    acc[1][3] = mfma32(af1, bf3, acc[1][3]);             \
    acc[2][0] = mfma32(af2, bf0, acc[2][0]);             \
    acc[2][1] = mfma32(af2, bf1, acc[2][1]);             \
    acc[2][2] = mfma32(af2, bf2, acc[2][2]);             \
    acc[2][3] = mfma32(af2, bf3, acc[2][3]);             \
    acc[3][0] = mfma32(af3, bf0, acc[3][0]);             \
    acc[3][1] = mfma32(af3, bf1, acc[3][1]);             \
    acc[3][2] = mfma32(af3, bf2, acc[3][2]);             \
    acc[3][3] = mfma32(af3, bf3, acc[3][3]);             \
    __builtin_amdgcn_s_setprio(0);                       \
  } while (0)

// -------------------------------- convert ---------------------------------
__global__ void cvt4_kernel(const float* __restrict__ x,
                            const float* __restrict__ w1,
                            const float* __restrict__ w2,
                            const float* __restrict__ w3,
                            _Float16* __restrict__ ox, _Float16* __restrict__ o1,
                            _Float16* __restrict__ o2, _Float16* __restrict__ o3) {
  const int bid = blockIdx.x;
  const float* src;
  _Float16* dst;
  int idx;
  if (bid < 8192) {
    src = x; dst = ox; idx = bid * 256 + threadIdx.x;
  } else if (bid < 10240) {
    src = w1; dst = o1; idx = (bid - 8192) * 256 + threadIdx.x;
  } else if (bid < 11264) {
    src = w2; dst = o2; idx = (bid - 10240) * 256 + threadIdx.x;
  } else {
    src = w3; dst = o3; idx = (bid - 11264) * 256 + threadIdx.x;
  }
  float4 v = reinterpret_cast<const float4*>(src)[idx];
  f16x4 o;
  o[0] = (_Float16)v.x; o[1] = (_Float16)v.y;
  o[2] = (_Float16)v.z; o[3] = (_Float16)v.w;
  reinterpret_cast<f16x4*>(dst)[idx] = o;
}

// ----------------------- GEMM 256x128 (QKV proj) ---------------------------
// BM=256 x BN=128, BK=32, 512 thr = 8 waves (4x2 of 64x64). Staged bytes per
// FLOP ~ (1/BM+1/BN): per-CU step staging (2 blk x 24 KB ~= 333 cy) balances
// MFMA (320 cy). 3-buffer rotation, ONE s_barrier per K-step, stage AFTER
// the barrier (distance-2 safe), counted vmcnt(3). asm ds_read keeps the
// loop waitcnt-opaque; chunk-XOR swizzle keeps reads conflict-free.
// Epilogue stages C through LDS for coalesced qk/vt stores.
#define GEMM_STAGE256(buf, kk)                                \
  do {                                                        \
    gl_lds16(pA0 + (kk), &lds[(buf)*8192 + wof]);             \
    gl_lds16(pA1 + (kk), &lds[(buf)*8192 + 4096 + wof]);      \
    gl_lds16(pB0 + (kk), &lds[24576 + (buf)*4096 + wof]);     \
  } while (0)

__global__ __launch_bounds__(512, 4) void gemm256_kernel(
    const _Float16* __restrict__ A, const _Float16* __restrict__ Bm,
    const float* __restrict__ bias_q, const float* __restrict__ bias_v,
    _Float16* __restrict__ qkbuf, _Float16* __restrict__ vtbuf) {
  const int K = 1024;
  __shared__ __align__(16) _Float16 lds[36864];  // 72 KB, reused by epilogue
  const int t = threadIdx.x;
  const int w = t >> 6;
  const int lane = t & 63;
  const int lq = lane & 15, lg = lane >> 4;
  const int wr = w >> 1, wc = w & 1;  // 4x2 waves of 64x64
  const int m0 = blockIdx.y * 256, n0 = blockIdx.x * 128;

  const int stc = ((t & 3) ^ ((t >> 3) & 3)) * 8;
  const _Float16* pA0 = A + (size_t)(m0 + (t >> 2)) * K + stc;
  const _Float16* pA1 = pA0 + (size_t)128 * K;
  const _Float16* pB0 = Bm + (size_t)(n0 + (t >> 2)) * K + stc;
  const int wof = w * 512;

  const int xsw = (lq >> 1) & 3;
  const uint32_t base = (uint32_t)(uintptr_t)(lds_f16p)&lds[0];
  const uint32_t aB0 =
      base + (uint32_t)((wr * 64 + lq) * 64 + ((lg ^ xsw) << 4));
  const uint32_t aB1 = aB0 + 16384;
  const uint32_t aB2 = aB0 + 32768;
  const uint32_t bB0 =
      base + 49152 + (uint32_t)((wc * 64 + lq) * 64 + ((lg ^ xsw) << 4));
  const uint32_t bB1 = bB0 + 8192;
  const uint32_t bB2 = bB0 + 16384;

  f32x4 acc[4][4];
#pragma unroll
  for (int mi = 0; mi < 4; ++mi)
#pragma unroll
    for (int ni = 0; ni < 4; ++ni) acc[mi][ni] = (f32x4){0.f, 0.f, 0.f, 0.f};

  GEMM_STAGE256(0, 0);
  GEMM_STAGE256(1, 32);
  for (int kt = 0; kt < 960; kt += 96) {
    GEMM_VM3;
    GEMM_BAR;
    GEMM_STAGE256(2, kt + 64);
    GEMM_COMPUTE(aB0, bB0);
    GEMM_VM3;
    GEMM_BAR;
    GEMM_STAGE256(0, kt + 96);
    GEMM_COMPUTE(aB1, bB1);
    GEMM_VM3;
    GEMM_BAR;
    GEMM_STAGE256(1, kt + 128);
    GEMM_COMPUTE(aB2, bB2);
  }
  GEMM_VM3;
  GEMM_BAR;
  GEMM_COMPUTE(aB0, bB0);
  GEMM_VM0;
  GEMM_BAR;
  GEMM_COMPUTE(aB1, bB1);

  // coalesced epilogue via LDS staging
  GEMM_BAR;
  _Float16* T = &lds[0];
  const bool isqk = (n0 < 2048);  // block-uniform (BN=128)
  const int bb = m0 >> 10, ii0 = m0 & 1023;
  if (isqk) {
    // T[256][136]: T[row][col] = C + bias_q (69.6 KB)
#pragma unroll
    for (int mi = 0; mi < 4; ++mi)
#pragma unroll
      for (int ni = 0; ni < 4; ++ni) {
        const int col = wc * 64 + ni * 16 + lq;
        const float bq = bias_q[n0 + col];
#pragma unroll
        for (int r = 0; r < 4; ++r) {
          const int row = wr * 64 + mi * 16 + lg * 4 + r;
          T[row * 136 + col] = (_Float16)(acc[mi][ni][r] + bq);
        }
      }
    __syncthreads();
    const int hh = n0 >> 7;
    _Float16* gb = qkbuf + ((size_t)((bb * 16 + hh) * 1024 + ii0)) * 128;
    const int row = t >> 1, half = t & 1;
    const int so = row * 136 + half * 64;
    const int go = row * 128 + half * 64;
#pragma unroll
    for (int j = 0; j < 8; ++j)
      *(f16x8*)(gb + go + j * 8) = *(const f16x8*)&T[so + j * 8];
  } else {
    // T[128][264]: T[col][row] = C^T + bias_v, f16x4-packed (67.6 KB)
    const int nn0 = n0 - 2048;
#pragma unroll
    for (int mi = 0; mi < 4; ++mi)
#pragma unroll
      for (int ni = 0; ni < 4; ++ni) {
        const int col = wc * 64 + ni * 16 + lq;
        const float bv = bias_v[nn0 + col];
        const int row0 = wr * 64 + mi * 16 + lg * 4;
        f16x4 p;
#pragma unroll
        for (int r = 0; r < 4; ++r) p[r] = (_Float16)(acc[mi][ni][r] + bv);
        *(f16x4*)&T[col * 264 + row0] = p;
      }
    __syncthreads();
    const int c = t >> 2, qd = t & 3;
    const int nn = nn0 + c;
    const int hh = nn >> 6, dv = nn & 63;
    _Float16* gb = vtbuf + ((size_t)((bb * 16 + hh) * 64 + dv)) * 1024 +
                   ii0 + qd * 64;
    const int so = c * 264 + qd * 64;
#pragma unroll
    for (int j = 0; j < 8; ++j)
      *(f16x8*)(gb + j * 8) = *(const f16x8*)&T[so + j * 8];
  }
}

// ----------------------- GEMM 128x128 (out proj) ---------------------------
// 128x128, 256 thr = 4 waves (2x2 of 64x64), grid 8x64 = 512 blocks = 2/CU
// (the 256-row tile would give only 1 block/CU at N=1024 -> R16 regression).
// Same one-barrier 3-buffer pipeline; fp32 + bias epilogue (row-major,
// already coalesced).
#define GEMM_STAGE128(buf, kk)                                     \
  do {                                                             \
    gl_lds16(pA0 + (kk), &lds[(buf)*4096 + wof]);                  \
    gl_lds16(pA1 + (kk), &lds[(buf)*4096 + 2048 + wof]);           \
    gl_lds16(pB0 + (kk), &lds[12288 + (buf)*4096 + wof]);          \
    gl_lds16(pB1 + (kk), &lds[12288 + (buf)*4096 + 2048 + wof]);   \
  } while (0)

__global__ __launch_bounds__(256, 3) void gemm128_kernel(
    const _Float16* __restrict__ A, const _Float16* __restrict__ Bm,
    const float* __restrict__ bias_o, float* __restrict__ outf) {
  const int K = 1024, N = 1024;
  __shared__ __align__(16) _Float16 lds[6 * 4096];
  const int t = threadIdx.x;
  const int w = t >> 6;
  const int lane = t & 63;
  const int lq = lane & 15, lg = lane >> 4;
  const int wr = w >> 1, wc = w & 1;
  const int m0 = blockIdx.y * 128, n0 = blockIdx.x * 128;

  const int stc = ((t & 3) ^ ((t >> 3) & 3)) * 8;
  const _Float16* pA0 = A + (size_t)(m0 + (t >> 2)) * K + stc;
  const _Float16* pA1 = pA0 + (size_t)64 * K;
  const _Float16* pB0 = Bm + (size_t)(n0 + (t >> 2)) * K + stc;
  const _Float16* pB1 = pB0 + (size_t)64 * K;
  const int wof = w * 512;

  const int xsw = (lq >> 1) & 3;
  const uint32_t base = (uint32_t)(uintptr_t)(lds_f16p)&lds[0];
  const uint32_t aB0 =
      base + (uint32_t)((wr * 64 + lq) * 64 + ((lg ^ xsw) << 4));
  const uint32_t aB1 = aB0 + 8192;
  const uint32_t aB2 = aB0 + 16384;
  const uint32_t bB0 =
      base + 24576 + (uint32_t)((wc * 64 + lq) * 64 + ((lg ^ xsw) << 4));
  const uint32_t bB1 = bB0 + 8192;
  const uint32_t bB2 = bB0 + 16384;

  f32x4 acc[4][4];
#pragma unroll
  for (int mi = 0; mi < 4; ++mi)
#pragma unroll
    for (int ni = 0; ni < 4; ++ni) acc[mi][ni] = (f32x4){0.f, 0.f, 0.f, 0.f};

  GEMM_STAGE128(0, 0);
  GEMM_STAGE128(1, 32);
  for (int kt = 0; kt < 960; kt += 96) {
    GEMM_VM4;
    GEMM_BAR;
    GEMM_STAGE128(2, kt + 64);
    GEMM_COMPUTE(aB0, bB0);
    GEMM_VM4;
    GEMM_BAR;
    GEMM_STAGE128(0, kt + 96);
    GEMM_COMPUTE(aB1, bB1);
    GEMM_VM4;
    GEMM_BAR;
    GEMM_STAGE128(1, kt + 128);
    GEMM_COMPUTE(aB2, bB2);
  }
  GEMM_VM4;
  GEMM_BAR;
  GEMM_COMPUTE(aB0, bB0);
  GEMM_VM0;
  GEMM_BAR;
  GEMM_COMPUTE(aB1, bB1);

#pragma unroll
  for (int mi = 0; mi < 4; ++mi)
#pragma unroll
    for (int ni = 0; ni < 4; ++ni)
#pragma unroll
      for (int r = 0; r < 4; ++r) {
        const int mg = m0 + wr * 64 + mi * 16 + lg * 4 + r;
        const int ng = n0 + wc * 64 + ni * 16 + lq;
        outf[(size_t)mg * N + ng] = acc[mi][ni][r] + bias_o[ng];
      }
}

// ------------------------------- attention --------------------------------
// R14 known-good version (4 waves, 1024 blocks, typed LDS reads, single
// __syncthreads, compiler scheduling). Block owns q-tile PAIR (tA=b4,
// tB=15-b4) of one (b,h): constant work per block; barrier-synced LDS
// staging of K/V tiles (KVBLK=64), double-buffered, swizzled.
__device__ __forceinline__ void stage_kv(const _Float16* __restrict__ kb,
                                         const _Float16* __restrict__ vtb,
                                         int j0, _Float16* kl, _Float16* vl,
                                         int t) {
  const int r0 = t >> 3, c0 = t & 7;
  const int r1 = r0 + 32;
  const int kc0 = c0 ^ (r0 & 7), kc1 = c0 ^ (r1 & 7);
  gl_lds16(kb + (size_t)(j0 + r0) * 128 + kc0 * 8, kl + t * 8);
  gl_lds16(kb + (size_t)(j0 + r1) * 128 + kc1 * 8, kl + (t + 256) * 8);
  gl_lds16(vtb + (size_t)r0 * 1024 + j0 + kc0 * 8, vl + t * 8);
  gl_lds16(vtb + (size_t)r1 * 1024 + j0 + kc1 * 8, vl + (t + 256) * 8);
}

__device__ __forceinline__ void softmax16(f32x4 (&st)[4], f16x4 (&ph)[4],
                                          int qi, int j0, bool far,
                                          const float* __restrict__ tab,
                                          float t128, int lg4, float& m_run,
                                          float& l_part, f32x4 (&oacc)[4]) {
  float xs[16];
  float lmax = NEG_INF;
  if (far) {
#pragma unroll
    for (int js = 0; js < 4; ++js)
#pragma unroll
      for (int r = 0; r < 4; ++r) {
        const float xv = fmaf(st[js][r], 0.125f * LOG2E, t128);
        xs[js * 4 + r] = xv;
        lmax = fmaxf(lmax, xv);
      }
  } else {
#pragma unroll
    for (int js = 0; js < 4; ++js)
#pragma unroll
      for (int r = 0; r < 4; ++r) {
        const int jj = j0 + js * 16 + lg4 + r;
        const int dd = qi - jj;
        const int idx = dd < 0 ? 0 : (dd > 128 ? 128 : dd);
        const float xv =
            (dd < 0) ? NEG_INF : fmaf(st[js][r], 0.125f * LOG2E, tab[idx]);
        xs[js * 4 + r] = xv;
        lmax = fmaxf(lmax, xv);
      }
  }
  if (__any(lmax > m_run + 8.0f)) {
    float tmax = fmaxf(lmax, __shfl_xor(lmax, 16));
    tmax = fmaxf(tmax, __shfl_xor(tmax, 32));
    const float m_new = fmaxf(m_run, tmax);
    const float sf = EXP2(m_run - m_new);
    m_run = m_new;
    l_part *= sf;
    f32x4 sfv;
#pragma unroll
    for (int r = 0; r < 4; ++r) sfv[r] = __shfl(sf, lg4 + r);
#pragma unroll
    for (int db = 0; db < 4; ++db) oacc[db] *= sfv;
  }
  float ls = 0.f;
#pragma unroll
  for (int js = 0; js < 4; ++js)
#pragma unroll
    for (int r = 0; r < 4; ++r) {
      const float p = EXP2(xs[js * 4 + r] - m_run);
      ls += p;
      ph[js][r] = (_Float16)p;
    }
  l_part += ls;
}

__global__ __launch_bounds__(256, 4) void attn_kernel(
    const _Float16* __restrict__ qk,  // [B*H][1024][128] (q | k)
    const _Float16* __restrict__ vt,  // [B*H][64][1024]  (V^T)
    const float* __restrict__ bias,   // [32][16]
    _Float16* __restrict__ ao) {      // [B][1024][H*64]
  __shared__ __align__(16) _Float16 kls[2][64 * 64];
  __shared__ __align__(16) _Float16 vls[2][64 * 64];
  __shared__ float tab[132];
  const int t = threadIdx.x;
  const int bid = blockIdx.x;
  const int bh = (bid & 7) * 16 + (bid >> 6);
  const int b4 = (bid >> 3) & 7;
  const int h = bh & 15, b = bh >> 4;
  if (t < 129) {
    const int bucket =
        (t <= 16) ? t : 16 + (int)(log((double)(t - 15)) * 15.0 / log(113.0));
    tab[t] = bias[bucket * 16 + h] * LOG2E;
  }

  const int w = t >> 6, lane = t & 63;
  const int lq = lane & 15, lg = lane >> 4;
  const int lg4 = lg * 4, lg8 = lg * 8;
  const int tA = b4, tB = 15 - b4;
  const int q0A = tA * 64 + w * 16, q0B = tB * 64 + w * 16;
  const int qA = q0A + lq, qB = q0B + lq;
  const _Float16* qkb = qk + (size_t)bh * 1024 * 128;
  const _Float16* kb = qkb + 64;
  const _Float16* vtb = vt + (size_t)bh * 64 * 1024;

  const f16x8 qfA0 = *(const f16x8*)&qkb[qA * 128 + lg8];
  const f16x8 qfA1 = *(const f16x8*)&qkb[qA * 128 + 32 + lg8];
  const f16x8 qfB0 = *(const f16x8*)&qkb[qB * 128 + lg8];
  const f16x8 qfB1 = *(const f16x8*)&qkb[qB * 128 + 32 + lg8];

  f32x4 oA[4], oB[4];
#pragma unroll
  for (int db = 0; db < 4; ++db) {
    oA[db] = (f32x4){0.f, 0.f, 0.f, 0.f};
    oB[db] = (f32x4){0.f, 0.f, 0.f, 0.f};
  }
  float mA = NEG_INF, lAp = 0.f, mB = NEG_INF, lBp = 0.f;

  stage_kv(kb, vtb, 0, kls[0], vls[0], t);
  __syncthreads();
  const float t128 = tab[128];
  const int krsw = lq & 7;
  const int vsw = (lq & 7) << 1;
  int cur = 0;

  for (int jt = 0; jt <= tB; ++jt) {
    const int j0 = jt * 64;
    if (jt < tB) stage_kv(kb, vtb, j0 + 64, kls[cur ^ 1], vls[cur ^ 1], t);
    const bool aact = (jt <= tA);
    const _Float16* kbf = kls[cur];
    const _Float16* vbf = vls[cur];

    f32x4 stA[4], stB[4];
#pragma unroll
    for (int js = 0; js < 4; ++js) {
      const int rowb = (js * 16 + lq) * 64;
      const f16x8 kf0 = *(const f16x8*)&kbf[rowb + ((lg ^ krsw) << 3)];
      const f16x8 kf1 = *(const f16x8*)&kbf[rowb + (((lg + 4) ^ krsw) << 3)];
      if (aact) {
        stA[js] = mfma32(kf0, qfA0, (f32x4){0.f, 0.f, 0.f, 0.f});
        stA[js] = mfma32(kf1, qfA1, stA[js]);
      }
      stB[js] = mfma32(kf0, qfB0, (f32x4){0.f, 0.f, 0.f, 0.f});
      stB[js] = mfma32(kf1, qfB1, stB[js]);
    }

    f16x4 phA[4], phB[4];
    if (aact)
      softmax16(stA, phA, qA, j0, q0A - j0 >= 192, tab, t128, lg4, mA, lAp,
                oA);
    softmax16(stB, phB, qB, j0, q0B - j0 >= 192, tab, t128, lg4, mB, lBp, oB);

#pragma unroll
    for (int js = 0; js < 4; ++js)
#pragma unroll
      for (int db = 0; db < 4; ++db) {
        const f16x4 vf = *(const f16x4*)&vbf[(db * 16 + lq) * 64 +
                                             ((((js << 2) + lg) ^ vsw) << 2)];
        if (aact) oA[db] = mfma16(phA[js], vf, oA[db]);
        oB[db] = mfma16(phB[js], vf, oB[db]);
      }

    __syncthreads();
    cur ^= 1;
  }

  _Float16* aob = ao + ((size_t)b * 1024) * 1024 + h * 64;
  {
    float lt = lAp + __shfl_xor(lAp, 16);
    lt += __shfl_xor(lt, 32);
    f32x4 linv;
#pragma unroll
    for (int r = 0; r < 4; ++r) linv[r] = 1.0f / __shfl(lt, lg4 + r);
#pragma unroll
    for (int db = 0; db < 4; ++db)
#pragma unroll
      for (int r = 0; r < 4; ++r)
        aob[(size_t)(q0A + lg4 + r) * 1024 + db * 16 + lq] =
            (_Float16)(oA[db][r] * linv[r]);
  }
  {
    float lt = lBp + __shfl_xor(lBp, 16);
    lt += __shfl_xor(lt, 32);
    f32x4 linv;
#pragma unroll
    for (int r = 0; r < 4; ++r) linv[r] = 1.0f / __shfl(lt, lg4 + r);
#pragma unroll
    for (int db = 0; db < 4; ++db)
#pragma unroll
      for (int r = 0; r < 4; ++r)
        aob[(size_t)(q0B + lg4 + r) * 1024 + db * 16 + lq] =
            (_Float16)(oB[db][r] * linv[r]);
  }
}

// -------------------------------- launch ----------------------------------
extern "C" void kernel_launch(void* const* d_in, const int* in_sizes, int n_in,
                              void* d_out, int out_size, void* d_ws,
                              size_t ws_size, hipStream_t stream) {
  const float* x = (const float*)d_in[0];
  const float* qk_w = (const float*)d_in[1];
  const float* qk_b = (const float*)d_in[2];
  const float* v_w = (const float*)d_in[3];
  const float* v_b = (const float*)d_in[4];
  const float* out_w = (const float*)d_in[5];
  const float* out_b = (const float*)d_in[6];
  const float* bias = (const float*)d_in[7];
  float* out = (float*)d_out;

  // workspace (fp16 elems): xb 8M | wb 3M | owb 1M | qk 16M | vt 8M | ao 8M
  _Float16* xb = (_Float16*)d_ws;
  _Float16* wb = xb + (size_t)8388608;
  _Float16* owb = wb + (size_t)3145728;
  _Float16* qkbuf = owb + (size_t)1048576;
  _Float16* vtbuf = qkbuf + (size_t)16777216;
  _Float16* ao = vtbuf + (size_t)8388608;

  // all conversions in one launch
  cvt4_kernel<<<12288, 256, 0, stream>>>(x, qk_w, v_w, out_w, xb, wb,
                                         wb + 2097152, owb);

  // fused QKV projection: M=8192, N=3072 (2048 qk | 1024 v), K=1024
  gemm256_kernel<<<dim3(24, 32), 512, 0, stream>>>(xb, wb, qk_b, v_b, qkbuf,
                                                   vtbuf);

  // flash attention: 8 balanced blocks per (b,h)
  attn_kernel<<<1024, 256, 0, stream>>>(qkbuf, vtbuf, bias, ao);

  // output projection: M=8192, N=1024, K=1024 -> fp32 d_out (2 blocks/CU)
  gemm128_kernel<<<dim3(8, 64), 256, 0, stream>>>(ao, owb, out_b, out);
}

// Round 18
// 160.533 us; speedup vs baseline: 1.0138x; 1.0138x over previous
//
#include <hip/hip_runtime.h>
#include <cmath>

// ---------------------------------------------------------------------------
// T5 MHSA: x->(QKV proj, f16 MFMA GEMM) -> flash attn w/ T5 bias -> out proj
// All matmuls on MFMA. fp16 intermediates, fp32 accum.
// ---------------------------------------------------------------------------

typedef _Float16 f16x8 __attribute__((ext_vector_type(8)));
typedef _Float16 f16x4 __attribute__((ext_vector_type(4)));
typedef float    f32x4 __attribute__((ext_vector_type(4)));

#define NEG_INF (-__builtin_inff())
#define LOG2E 1.4426950408889634f

#if __has_builtin(__builtin_amdgcn_exp2f)
#define EXP2(x) __builtin_amdgcn_exp2f(x)
#else
#define EXP2(x) exp2f(x)
#endif

__device__ __forceinline__ void gl_lds16(const void* g, void* l) {
  __builtin_amdgcn_global_load_lds(
      (__attribute__((address_space(1))) void*)g,
      (__attribute__((address_space(3))) void*)l,
      16, 0, 0);
}

__device__ __forceinline__ f32x4 mfma32(f16x8 a, f16x8 b, f32x4 c) {
  return __builtin_amdgcn_mfma_f32_16x16x32_f16(a, b, c, 0, 0, 0);
}
__device__ __forceinline__ f32x4 mfma16(f16x4 a, f16x4 b, f32x4 c) {
  return __builtin_amdgcn_mfma_f32_16x16x16f16(a, b, c, 0, 0, 0);
}

typedef __attribute__((address_space(3))) _Float16* lds_f16p;

#define DSR(d, a, o) \
  asm volatile("ds_read_b128 %0, %1 offset:" o : "=v"(d) : "v"(a))

#define GEMM_VM6 asm volatile("s_waitcnt vmcnt(6)" ::: "memory")
#define GEMM_VM4 asm volatile("s_waitcnt vmcnt(4)" ::: "memory")
#define GEMM_VM0 asm volatile("s_waitcnt vmcnt(0)" ::: "memory")
#define GEMM_BAR __builtin_amdgcn_s_barrier()

// -------------------------------- convert ---------------------------------
__global__ void cvt4_kernel(const float* __restrict__ x,
                            const float* __restrict__ w1,
                            const float* __restrict__ w2,
                            const float* __restrict__ w3,
                            _Float16* __restrict__ ox, _Float16* __restrict__ o1,
                            _Float16* __restrict__ o2, _Float16* __restrict__ o3) {
  const int bid = blockIdx.x;
  const float* src;
  _Float16* dst;
  int idx;
  if (bid < 8192) {
    src = x; dst = ox; idx = bid * 256 + threadIdx.x;
  } else if (bid < 10240) {
    src = w1; dst = o1; idx = (bid - 8192) * 256 + threadIdx.x;
  } else if (bid < 11264) {
    src = w2; dst = o2; idx = (bid - 10240) * 256 + threadIdx.x;
  } else {
    src = w3; dst = o3; idx = (bid - 11264) * 256 + threadIdx.x;
  }
  float4 v = reinterpret_cast<const float4*>(src)[idx];
  f16x4 o;
  o[0] = (_Float16)v.x; o[1] = (_Float16)v.y;
  o[2] = (_Float16)v.z; o[3] = (_Float16)v.w;
  reinterpret_cast<f16x4*>(dst)[idx] = o;
}

// ----------------------- GEMM 256x128 wide-wave (QKV) ----------------------
// BM=256 x BN=128, BK=32, 256 thr = 4 waves, each owning a 64x128 out tile
// (acc[4][8]). Rationale: the 64x64-wave version is LDS-read-BW-bound
// (8KB/16 MFMA = 512 B/MFMA -> 32% MfmaUtil cap, measured 30.9%); 64x128
// reads 12KB/32 MFMA = 384 B/MFMA -> cap ~43%. 3-buffer rotation (72 KB),
// ONE s_barrier per K-step, stage AFTER the barrier (distance-2 safe),
// counted vmcnt(6) (6 loads/thread/stage). Chunk-XOR swizzle on write
// ((row>>1)&3) and read ((lq>>1)&3) keeps ds_read_b128 conflict-free.
// Epilogue stages C through LDS for coalesced qk/vt stores.
#define GEMM_STAGEW(buf, kk)                                        \
  do {                                                              \
    gl_lds16(pA0 + (kk), &lds[(buf)*8192 + wof]);                   \
    gl_lds16(pA1 + (kk), &lds[(buf)*8192 + 2048 + wof]);            \
    gl_lds16(pA2 + (kk), &lds[(buf)*8192 + 4096 + wof]);            \
    gl_lds16(pA3 + (kk), &lds[(buf)*8192 + 6144 + wof]);            \
    gl_lds16(pB0 + (kk), &lds[24576 + (buf)*4096 + wof]);           \
    gl_lds16(pB1 + (kk), &lds[24576 + (buf)*4096 + 2048 + wof]);    \
  } while (0)

#define GEMM_COMPUTEW(aB, bB)                                  \
  do {                                                         \
    f16x8 af[4], bf[8];                                        \
    DSR(af[0], aB, "0");                                       \
    DSR(af[1], aB, "1024");                                    \
    DSR(af[2], aB, "2048");                                    \
    DSR(af[3], aB, "3072");                                    \
    DSR(bf[0], bB, "0");                                       \
    DSR(bf[1], bB, "1024");                                    \
    DSR(bf[2], bB, "2048");                                    \
    DSR(bf[3], bB, "3072");                                    \
    DSR(bf[4], bB, "4096");                                    \
    DSR(bf[5], bB, "5120");                                    \
    DSR(bf[6], bB, "6144");                                    \
    DSR(bf[7], bB, "7168");                                    \
    asm volatile("s_waitcnt lgkmcnt(6)" ::: "memory");         \
    __builtin_amdgcn_sched_barrier(0);                         \
    __builtin_amdgcn_s_setprio(1);                             \
    _Pragma("unroll") for (int mi = 0; mi < 4; ++mi)           \
      _Pragma("unroll") for (int ni = 0; ni < 2; ++ni)         \
        acc[mi][ni] = mfma32(af[mi], bf[ni], acc[mi][ni]);     \
    asm volatile("s_waitcnt lgkmcnt(0)" ::: "memory");         \
    __builtin_amdgcn_sched_barrier(0);                         \
    _Pragma("unroll") for (int mi = 0; mi < 4; ++mi)           \
      _Pragma("unroll") for (int ni = 2; ni < 8; ++ni)         \
        acc[mi][ni] = mfma32(af[mi], bf[ni], acc[mi][ni]);     \
    __builtin_amdgcn_s_setprio(0);                             \
  } while (0)

__global__ __launch_bounds__(256, 2) void gemmw_kernel(
    const _Float16* __restrict__ A, const _Float16* __restrict__ Bm,
    const float* __restrict__ bias_q, const float* __restrict__ bias_v,
    _Float16* __restrict__ qkbuf, _Float16* __restrict__ vtbuf) {
  const int K = 1024;
  __shared__ __align__(16) _Float16 lds[36864];  // 72 KB, reused by epilogue
  const int t = threadIdx.x;
  const int w = t >> 6;
  const int lane = t & 63;
  const int lq = lane & 15, lg = lane >> 4;
  const int m0 = blockIdx.y * 256, n0 = blockIdx.x * 128;

  // staging: thread t -> row chunk*64 + (t>>2), SOURCE k-chunk
  // (t&3)^((t>>3)&3) (inverse of the read-side slot swizzle)
  const int stc = ((t & 3) ^ ((t >> 3) & 3)) * 8;
  const _Float16* pA0 = A + (size_t)(m0 + (t >> 2)) * K + stc;
  const _Float16* pA1 = pA0 + (size_t)64 * K;
  const _Float16* pA2 = pA0 + (size_t)128 * K;
  const _Float16* pA3 = pA0 + (size_t)192 * K;
  const _Float16* pB0 = Bm + (size_t)(n0 + (t >> 2)) * K + stc;
  const _Float16* pB1 = pB0 + (size_t)64 * K;
  const int wof = w * 512;  // wave-uniform LDS base (HW adds lane*16B)

  const int xsw = (lq >> 1) & 3;
  const uint32_t base = (uint32_t)(uintptr_t)(lds_f16p)&lds[0];
  const uint32_t aB0 =
      base + (uint32_t)((w * 64 + lq) * 64 + ((lg ^ xsw) << 4));
  const uint32_t aB1 = aB0 + 16384;
  const uint32_t aB2 = aB0 + 32768;
  const uint32_t bB0 =
      base + 49152 + (uint32_t)(lq * 64 + ((lg ^ xsw) << 4));
  const uint32_t bB1 = bB0 + 8192;
  const uint32_t bB2 = bB0 + 16384;

  f32x4 acc[4][8];
#pragma unroll
  for (int mi = 0; mi < 4; ++mi)
#pragma unroll
    for (int ni = 0; ni < 8; ++ni) acc[mi][ni] = (f32x4){0.f, 0.f, 0.f, 0.f};

  // prologue: stage tiles 0,1 (12 loads outstanding)
  GEMM_STAGEW(0, 0);
  GEMM_STAGEW(1, 32);
  // main: steps 0..29; step s: wait tile s (vmcnt 6), stage tile s+2
  for (int kt = 0; kt < 960; kt += 96) {
    GEMM_VM6;
    GEMM_BAR;
    GEMM_STAGEW(2, kt + 64);
    GEMM_COMPUTEW(aB0, bB0);
    GEMM_VM6;
    GEMM_BAR;
    GEMM_STAGEW(0, kt + 96);
    GEMM_COMPUTEW(aB1, bB1);
    GEMM_VM6;
    GEMM_BAR;
    GEMM_STAGEW(1, kt + 128);
    GEMM_COMPUTEW(aB2, bB2);
  }
  GEMM_VM6;  // tile 30 landed (tile 31's 6 loads in flight)
  GEMM_BAR;
  GEMM_COMPUTEW(aB0, bB0);
  GEMM_VM0;
  GEMM_BAR;
  GEMM_COMPUTEW(aB1, bB1);

  // ------------------- coalesced epilogue via LDS staging -------------------
  GEMM_BAR;  // all waves done reading frag buffers; lds reusable
  _Float16* T = &lds[0];
  const bool isqk = (n0 < 2048);  // block-uniform (BN=128)
  const int bb = m0 >> 10, ii0 = m0 & 1023;
  if (isqk) {
    // T[256][136]: T[row][col] = C + bias_q (69.6 KB)
#pragma unroll
    for (int mi = 0; mi < 4; ++mi)
#pragma unroll
      for (int ni = 0; ni < 8; ++ni) {
        const int col = ni * 16 + lq;
        const float bq = bias_q[n0 + col];
#pragma unroll
        for (int r = 0; r < 4; ++r) {
          const int row = w * 64 + mi * 16 + lg * 4 + r;
          T[row * 136 + col] = (_Float16)(acc[mi][ni][r] + bq);
        }
      }
    __syncthreads();
    const int hh = n0 >> 7;  // one head per 128-wide tile
    _Float16* gb = qkbuf + ((size_t)((bb * 16 + hh) * 1024 + ii0)) * 128;
#pragma unroll
    for (int h2 = 0; h2 < 2; ++h2) {
      const int row = h2 * 128 + (t >> 1);
      const int so = row * 136 + (t & 1) * 64;
      const int go = row * 128 + (t & 1) * 64;
#pragma unroll
      for (int j = 0; j < 8; ++j)
        *(f16x8*)(gb + go + j * 8) = *(const f16x8*)&T[so + j * 8];
    }
  } else {
    // T[128][264]: T[col][row] = C^T + bias_v, f16x4-packed (67.6 KB)
    const int nn0 = n0 - 2048;
#pragma unroll
    for (int mi = 0; mi < 4; ++mi)
#pragma unroll
      for (int ni = 0; ni < 8; ++ni) {
        const int col = ni * 16 + lq;
        const float bv = bias_v[nn0 + col];
        const int row0 = w * 64 + mi * 16 + lg * 4;
        f16x4 p;
#pragma unroll
        for (int r = 0; r < 4; ++r) p[r] = (_Float16)(acc[mi][ni][r] + bv);
        *(f16x4*)&T[col * 264 + row0] = p;
      }
    __syncthreads();
    const int c = t >> 1, half = t & 1;
    const int nn = nn0 + c;
    const int hh = nn >> 6, dv = nn & 63;
    _Float16* gb = vtbuf + ((size_t)((bb * 16 + hh) * 64 + dv)) * 1024 +
                   ii0 + half * 128;
    const int so = c * 264 + half * 128;
#pragma unroll
    for (int j = 0; j < 16; ++j)
      *(f16x8*)(gb + j * 8) = *(const f16x8*)&T[so + j * 8];
  }
}

// ----------------------- GEMM 128x128 (out proj) ---------------------------
// 128x128, 256 thr = 4 waves (2x2 of 64x64), grid 8x64 = 512 blocks = 2/CU.
// One-barrier 3-buffer pipeline; fp32 + bias epilogue (row-major, coalesced).
#define GEMM_COMPUTE(aB, bB)                             \
  do {                                                   \
    f16x8 af0, af1, af2, af3, bf0, bf1, bf2, bf3;        \
    DSR(af0, aB, "0");                                   \
    DSR(bf0, bB, "0");                                   \
    DSR(af1, aB, "1024");                                \
    DSR(bf1, bB, "1024");                                \
    DSR(af2, aB, "2048");                                \
    DSR(bf2, bB, "2048");                                \
    DSR(af3, aB, "3072");                                \
    DSR(bf3, bB, "3072");                                \
    asm volatile("s_waitcnt lgkmcnt(4)" ::: "memory");   \
    __builtin_amdgcn_sched_barrier(0);                   \
    __builtin_amdgcn_s_setprio(1);                       \
    acc[0][0] = mfma32(af0, bf0, acc[0][0]);             \
    acc[0][1] = mfma32(af0, bf1, acc[0][1]);             \
    acc[1][0] = mfma32(af1, bf0, acc[1][0]);             \
    acc[1][1] = mfma32(af1, bf1, acc[1][1]);             \
    asm volatile("s_waitcnt lgkmcnt(0)" ::: "memory");   \
    __builtin_amdgcn_sched_barrier(0);                   \
    acc[0][2] = mfma32(af0, bf2, acc[0][2]);             \
    acc[0][3] = mfma32(af0, bf3, acc[0][3]);             \
    acc[1][2] = mfma32(af1, bf2, acc[1][2]);             \
    acc[1][3] = mfma32(af1, bf3, acc[1][3]);             \
    acc[2][0] = mfma32(af2, bf0, acc[2][0]);             \
    acc[2][1] = mfma32(af2, bf1, acc[2][1]);             \
    acc[2][2] = mfma32(af2, bf2, acc[2][2]);             \
    acc[2][3] = mfma32(af2, bf3, acc[2][3]);             \
    acc[3][0] = mfma32(af3, bf0, acc[3][0]);             \
    acc[3][1] = mfma32(af3, bf1, acc[3][1]);             \
    acc[3][2] = mfma32(af3, bf2, acc[3][2]);             \
    acc[3][3] = mfma32(af3, bf3, acc[3][3]);             \
    __builtin_amdgcn_s_setprio(0);                       \
  } while (0)

#define GEMM_STAGE128(buf, kk)                                     \
  do {                                                             \
    gl_lds16(pA0 + (kk), &lds[(buf)*4096 + wof]);                  \
    gl_lds16(pA1 + (kk), &lds[(buf)*4096 + 2048 + wof]);           \
    gl_lds16(pB0 + (kk), &lds[12288 + (buf)*4096 + wof]);          \
    gl_lds16(pB1 + (kk), &lds[12288 + (buf)*4096 + 2048 + wof]);   \
  } while (0)

__global__ __launch_bounds__(256, 3) void gemm128_kernel(
    const _Float16* __restrict__ A, const _Float16* __restrict__ Bm,
    const float* __restrict__ bias_o, float* __restrict__ outf) {
  const int K = 1024, N = 1024;
  __shared__ __align__(16) _Float16 lds[6 * 4096];
  const int t = threadIdx.x;
  const int w = t >> 6;
  const int lane = t & 63;
  const int lq = lane & 15, lg = lane >> 4;
  const int wr = w >> 1, wc = w & 1;
  const int m0 = blockIdx.y * 128, n0 = blockIdx.x * 128;

  const int stc = ((t & 3) ^ ((t >> 3) & 3)) * 8;
  const _Float16* pA0 = A + (size_t)(m0 + (t >> 2)) * K + stc;
  const _Float16* pA1 = pA0 + (size_t)64 * K;
  const _Float16* pB0 = Bm + (size_t)(n0 + (t >> 2)) * K + stc;
  const _Float16* pB1 = pB0 + (size_t)64 * K;
  const int wof = w * 512;

  const int xsw = (lq >> 1) & 3;
  const uint32_t base = (uint32_t)(uintptr_t)(lds_f16p)&lds[0];
  const uint32_t aB0 =
      base + (uint32_t)((wr * 64 + lq) * 64 + ((lg ^ xsw) << 4));
  const uint32_t aB1 = aB0 + 8192;
  const uint32_t aB2 = aB0 + 16384;
  const uint32_t bB0 =
      base + 24576 + (uint32_t)((wc * 64 + lq) * 64 + ((lg ^ xsw) << 4));
  const uint32_t bB1 = bB0 + 8192;
  const uint32_t bB2 = bB0 + 16384;

  f32x4 acc[4][4];
#pragma unroll
  for (int mi = 0; mi < 4; ++mi)
#pragma unroll
    for (int ni = 0; ni < 4; ++ni) acc[mi][ni] = (f32x4){0.f, 0.f, 0.f, 0.f};

  GEMM_STAGE128(0, 0);
  GEMM_STAGE128(1, 32);
  for (int kt = 0; kt < 960; kt += 96) {
    GEMM_VM4;
    GEMM_BAR;
    GEMM_STAGE128(2, kt + 64);
    GEMM_COMPUTE(aB0, bB0);
    GEMM_VM4;
    GEMM_BAR;
    GEMM_STAGE128(0, kt + 96);
    GEMM_COMPUTE(aB1, bB1);
    GEMM_VM4;
    GEMM_BAR;
    GEMM_STAGE128(1, kt + 128);
    GEMM_COMPUTE(aB2, bB2);
  }
  GEMM_VM4;
  GEMM_BAR;
  GEMM_COMPUTE(aB0, bB0);
  GEMM_VM0;
  GEMM_BAR;
  GEMM_COMPUTE(aB1, bB1);

#pragma unroll
  for (int mi = 0; mi < 4; ++mi)
#pragma unroll
    for (int ni = 0; ni < 4; ++ni)
#pragma unroll
      for (int r = 0; r < 4; ++r) {
        const int mg = m0 + wr * 64 + mi * 16 + lg * 4 + r;
        const int ng = n0 + wc * 64 + ni * 16 + lq;
        outf[(size_t)mg * N + ng] = acc[mi][ni][r] + bias_o[ng];
      }
}

// ------------------------------- attention --------------------------------
// R14 known-good version (4 waves, 1024 blocks, typed LDS reads, single
// __syncthreads, compiler scheduling). Block owns q-tile PAIR (tA=b4,
// tB=15-b4) of one (b,h): constant work per block; barrier-synced LDS
// staging of K/V tiles (KVBLK=64), double-buffered, swizzled.
__device__ __forceinline__ void stage_kv(const _Float16* __restrict__ kb,
                                         const _Float16* __restrict__ vtb,
                                         int j0, _Float16* kl, _Float16* vl,
                                         int t) {
  const int r0 = t >> 3, c0 = t & 7;
  const int r1 = r0 + 32;
  const int kc0 = c0 ^ (r0 & 7), kc1 = c0 ^ (r1 & 7);
  gl_lds16(kb + (size_t)(j0 + r0) * 128 + kc0 * 8, kl + t * 8);
  gl_lds16(kb + (size_t)(j0 + r1) * 128 + kc1 * 8, kl + (t + 256) * 8);
  gl_lds16(vtb + (size_t)r0 * 1024 + j0 + kc0 * 8, vl + t * 8);
  gl_lds16(vtb + (size_t)r1 * 1024 + j0 + kc1 * 8, vl + (t + 256) * 8);
}

__device__ __forceinline__ void softmax16(f32x4 (&st)[4], f16x4 (&ph)[4],
                                          int qi, int j0, bool far,
                                          const float* __restrict__ tab,
                                          float t128, int lg4, float& m_run,
                                          float& l_part, f32x4 (&oacc)[4]) {
  float xs[16];
  float lmax = NEG_INF;
  if (far) {
#pragma unroll
    for (int js = 0; js < 4; ++js)
#pragma unroll
      for (int r = 0; r < 4; ++r) {
        const float xv = fmaf(st[js][r], 0.125f * LOG2E, t128);
        xs[js * 4 + r] = xv;
        lmax = fmaxf(lmax, xv);
      }
  } else {
#pragma unroll
    for (int js = 0; js < 4; ++js)
#pragma unroll
      for (int r = 0; r < 4; ++r) {
        const int jj = j0 + js * 16 + lg4 + r;
        const int dd = qi - jj;
        const int idx = dd < 0 ? 0 : (dd > 128 ? 128 : dd);
        const float xv =
            (dd < 0) ? NEG_INF : fmaf(st[js][r], 0.125f * LOG2E, tab[idx]);
        xs[js * 4 + r] = xv;
        lmax = fmaxf(lmax, xv);
      }
  }
  if (__any(lmax > m_run + 8.0f)) {
    float tmax = fmaxf(lmax, __shfl_xor(lmax, 16));
    tmax = fmaxf(tmax, __shfl_xor(tmax, 32));
    const float m_new = fmaxf(m_run, tmax);
    const float sf = EXP2(m_run - m_new);
    m_run = m_new;
    l_part *= sf;
    f32x4 sfv;
#pragma unroll
    for (int r = 0; r < 4; ++r) sfv[r] = __shfl(sf, lg4 + r);
#pragma unroll
    for (int db = 0; db < 4; ++db) oacc[db] *= sfv;
  }
  float ls = 0.f;
#pragma unroll
  for (int js = 0; js < 4; ++js)
#pragma unroll
    for (int r = 0; r < 4; ++r) {
      const float p = EXP2(xs[js * 4 + r] - m_run);
      ls += p;
      ph[js][r] = (_Float16)p;
    }
  l_part += ls;
}

__global__ __launch_bounds__(256, 4) void attn_kernel(
    const _Float16* __restrict__ qk,  // [B*H][1024][128] (q | k)
    const _Float16* __restrict__ vt,  // [B*H][64][1024]  (V^T)
    const float* __restrict__ bias,   // [32][16]
    _Float16* __restrict__ ao) {      // [B][1024][H*64]
  __shared__ __align__(16) _Float16 kls[2][64 * 64];
  __shared__ __align__(16) _Float16 vls[2][64 * 64];
  __shared__ float tab[132];
  const int t = threadIdx.x;
  const int bid = blockIdx.x;
  const int bh = (bid & 7) * 16 + (bid >> 6);
  const int b4 = (bid >> 3) & 7;
  const int h = bh & 15, b = bh >> 4;
  if (t < 129) {
    const int bucket =
        (t <= 16) ? t : 16 + (int)(log((double)(t - 15)) * 15.0 / log(113.0));
    tab[t] = bias[bucket * 16 + h] * LOG2E;
  }

  const int w = t >> 6, lane = t & 63;
  const int lq = lane & 15, lg = lane >> 4;
  const int lg4 = lg * 4, lg8 = lg * 8;
  const int tA = b4, tB = 15 - b4;
  const int q0A = tA * 64 + w * 16, q0B = tB * 64 + w * 16;
  const int qA = q0A + lq, qB = q0B + lq;
  const _Float16* qkb = qk + (size_t)bh * 1024 * 128;
  const _Float16* kb = qkb + 64;
  const _Float16* vtb = vt + (size_t)bh * 64 * 1024;

  const f16x8 qfA0 = *(const f16x8*)&qkb[qA * 128 + lg8];
  const f16x8 qfA1 = *(const f16x8*)&qkb[qA * 128 + 32 + lg8];
  const f16x8 qfB0 = *(const f16x8*)&qkb[qB * 128 + lg8];
  const f16x8 qfB1 = *(const f16x8*)&qkb[qB * 128 + 32 + lg8];

  f32x4 oA[4], oB[4];
#pragma unroll
  for (int db = 0; db < 4; ++db) {
    oA[db] = (f32x4){0.f, 0.f, 0.f, 0.f};
    oB[db] = (f32x4){0.f, 0.f, 0.f, 0.f};
  }
  float mA = NEG_INF, lAp = 0.f, mB = NEG_INF, lBp = 0.f;

  stage_kv(kb, vtb, 0, kls[0], vls[0], t);
  __syncthreads();
  const float t128 = tab[128];
  const int krsw = lq & 7;
  const int vsw = (lq & 7) << 1;
  int cur = 0;

  for (int jt = 0; jt <= tB; ++jt) {
    const int j0 = jt * 64;
    if (jt < tB) stage_kv(kb, vtb, j0 + 64, kls[cur ^ 1], vls[cur ^ 1], t);
    const bool aact = (jt <= tA);
    const _Float16* kbf = kls[cur];
    const _Float16* vbf = vls[cur];

    f32x4 stA[4], stB[4];
#pragma unroll
    for (int js = 0; js < 4; ++js) {
      const int rowb = (js * 16 + lq) * 64;
      const f16x8 kf0 = *(const f16x8*)&kbf[rowb + ((lg ^ krsw) << 3)];
      const f16x8 kf1 = *(const f16x8*)&kbf[rowb + (((lg + 4) ^ krsw) << 3)];
      if (aact) {
        stA[js] = mfma32(kf0, qfA0, (f32x4){0.f, 0.f, 0.f, 0.f});
        stA[js] = mfma32(kf1, qfA1, stA[js]);
      }
      stB[js] = mfma32(kf0, qfB0, (f32x4){0.f, 0.f, 0.f, 0.f});
      stB[js] = mfma32(kf1, qfB1, stB[js]);
    }

    f16x4 phA[4], phB[4];
    if (aact)
      softmax16(stA, phA, qA, j0, q0A - j0 >= 192, tab, t128, lg4, mA, lAp,
                oA);
    softmax16(stB, phB, qB, j0, q0B - j0 >= 192, tab, t128, lg4, mB, lBp, oB);

#pragma unroll
    for (int js = 0; js < 4; ++js)
#pragma unroll
      for (int db = 0; db < 4; ++db) {
        const f16x4 vf = *(const f16x4*)&vbf[(db * 16 + lq) * 64 +
                                             ((((js << 2) + lg) ^ vsw) << 2)];
        if (aact) oA[db] = mfma16(phA[js], vf, oA[db]);
        oB[db] = mfma16(phB[js], vf, oB[db]);
      }

    __syncthreads();
    cur ^= 1;
  }

  _Float16* aob = ao + ((size_t)b * 1024) * 1024 + h * 64;
  {
    float lt = lAp + __shfl_xor(lAp, 16);
    lt += __shfl_xor(lt, 32);
    f32x4 linv;
#pragma unroll
    for (int r = 0; r < 4; ++r) linv[r] = 1.0f / __shfl(lt, lg4 + r);
#pragma unroll
    for (int db = 0; db < 4; ++db)
#pragma unroll
      for (int r = 0; r < 4; ++r)
        aob[(size_t)(q0A + lg4 + r) * 1024 + db * 16 + lq] =
            (_Float16)(oA[db][r] * linv[r]);
  }
  {
    float lt = lBp + __shfl_xor(lBp, 16);
    lt += __shfl_xor(lt, 32);
    f32x4 linv;
#pragma unroll
    for (int r = 0; r < 4; ++r) linv[r] = 1.0f / __shfl(lt, lg4 + r);
#pragma unroll
    for (int db = 0; db < 4; ++db)
#pragma unroll
      for (int r = 0; r < 4; ++r)
        aob[(size_t)(q0B + lg4 + r) * 1024 + db * 16 + lq] =
            (_Float16)(oB[db][r] * linv[r]);
  }
}

// -------------------------------- launch ----------------------------------
extern "C" void kernel_launch(void* const* d_in, const int* in_sizes, int n_in,
                              void* d_out, int out_size, void* d_ws,
                              size_t ws_size, hipStream_t stream) {
  const float* x = (const float*)d_in[0];
  const float* qk_w = (const float*)d_in[1];
  const float* qk_b = (const float*)d_in[2];
  const float* v_w = (const float*)d_in[3];
  const float* v_b = (const float*)d_in[4];
  const float* out_w = (const float*)d_in[5];
  const float* out_b = (const float*)d_in[6];
  const float* bias = (const float*)d_in[7];
  float* out = (float*)d_out;

  // workspace (fp16 elems): xb 8M | wb 3M | owb 1M | qk 16M | vt 8M | ao 8M
  _Float16* xb = (_Float16*)d_ws;
  _Float16* wb = xb + (size_t)8388608;
  _Float16* owb = wb + (size_t)3145728;
  _Float16* qkbuf = owb + (size_t)1048576;
  _Float16* vtbuf = qkbuf + (size_t)16777216;
  _Float16* ao = vtbuf + (size_t)8388608;

  // all conversions in one launch
  cvt4_kernel<<<12288, 256, 0, stream>>>(x, qk_w, v_w, out_w, xb, wb,
                                         wb + 2097152, owb);

  // fused QKV projection: M=8192, N=3072 (2048 qk | 1024 v), K=1024
  gemmw_kernel<<<dim3(24, 32), 256, 0, stream>>>(xb, wb, qk_b, v_b, qkbuf,
                                                 vtbuf);

  // flash attention: 8 balanced blocks per (b,h)
  attn_kernel<<<1024, 256, 0, stream>>>(qkbuf, vtbuf, bias, ao);

  // output projection: M=8192, N=1024, K=1024 -> fp32 d_out (2 blocks/CU)
  gemm128_kernel<<<dim3(8, 64), 256, 0, stream>>>(ao, owb, out_b, out);
}

// Round 19
// 157.704 us; speedup vs baseline: 1.0320x; 1.0179x over previous
//
#include <hip/hip_runtime.h>
#include <cmath>

// ---------------------------------------------------------------------------
// T5 MHSA: x->(QKV proj, f16 MFMA GEMM) -> flash attn w/ T5 bias -> out proj
// All matmuls on MFMA. fp16 intermediates, fp32 accum.
// R19 = R14 exact (session-best 157.4 us): later structural variants all
// measured neutral-to-worse (R15 170.1, R16 160.7, R17 162.7, R18 160.5).
// ---------------------------------------------------------------------------

typedef _Float16 f16x8 __attribute__((ext_vector_type(8)));
typedef _Float16 f16x4 __attribute__((ext_vector_type(4)));
typedef float    f32x4 __attribute__((ext_vector_type(4)));

#define NEG_INF (-__builtin_inff())
#define LOG2E 1.4426950408889634f

#if __has_builtin(__builtin_amdgcn_exp2f)
#define EXP2(x) __builtin_amdgcn_exp2f(x)
#else
#define EXP2(x) exp2f(x)
#endif

__device__ __forceinline__ void gl_lds16(const void* g, void* l) {
  __builtin_amdgcn_global_load_lds(
      (__attribute__((address_space(1))) void*)g,
      (__attribute__((address_space(3))) void*)l,
      16, 0, 0);
}

__device__ __forceinline__ f32x4 mfma32(f16x8 a, f16x8 b, f32x4 c) {
  return __builtin_amdgcn_mfma_f32_16x16x32_f16(a, b, c, 0, 0, 0);
}
__device__ __forceinline__ f32x4 mfma16(f16x4 a, f16x4 b, f32x4 c) {
  return __builtin_amdgcn_mfma_f32_16x16x16f16(a, b, c, 0, 0, 0);
}

typedef __attribute__((address_space(3))) _Float16* lds_f16p;

#define DSR(d, a, o) \
  asm volatile("ds_read_b128 %0, %1 offset:" o : "=v"(d) : "v"(a))

// -------------------------------- convert ---------------------------------
// single launch for all 4 fp32->fp16 conversions (saves 3 launch gaps)
__global__ void cvt4_kernel(const float* __restrict__ x,
                            const float* __restrict__ w1,
                            const float* __restrict__ w2,
                            const float* __restrict__ w3,
                            _Float16* __restrict__ ox, _Float16* __restrict__ o1,
                            _Float16* __restrict__ o2, _Float16* __restrict__ o3) {
  const int bid = blockIdx.x;
  const float* src;
  _Float16* dst;
  int idx;
  if (bid < 8192) {
    src = x; dst = ox; idx = bid * 256 + threadIdx.x;
  } else if (bid < 10240) {
    src = w1; dst = o1; idx = (bid - 8192) * 256 + threadIdx.x;
  } else if (bid < 11264) {
    src = w2; dst = o2; idx = (bid - 10240) * 256 + threadIdx.x;
  } else {
    src = w3; dst = o3; idx = (bid - 11264) * 256 + threadIdx.x;
  }
  float4 v = reinterpret_cast<const float4*>(src)[idx];
  f16x4 o;
  o[0] = (_Float16)v.x; o[1] = (_Float16)v.y;
  o[2] = (_Float16)v.z; o[3] = (_Float16)v.w;
  reinterpret_cast<f16x4*>(dst)[idx] = o;
}

// --------------------------------- GEMM -----------------------------------
// C = A(MxK) * Bm(NxK)^T.  128x128 tile, BK=32, 4 waves (2x2 of 64x64).
// 3-deep pipeline: triple-buffer LDS; stage tile s+2 during compute of tile
// s; counted vmcnt(8) keeps 2 tiles in flight across raw s_barriers. asm
// ds_read keeps the loop waitcnt-opaque. LDS chunk-XOR swizzle keeps
// ds_read conflict-free. MODE-0 epilogue stages the C-tile through LDS
// (freed after the K-loop) so qk/v outputs are written with fully-coalesced
// wave-wide f16x8 stores instead of 64 scattered scalar fp16 stores/thread.
#define GEMM_VM8 asm volatile("s_waitcnt vmcnt(8)" ::: "memory")
#define GEMM_VM4 asm volatile("s_waitcnt vmcnt(4)" ::: "memory")
#define GEMM_VM0 asm volatile("s_waitcnt vmcnt(0)" ::: "memory")
#define GEMM_BAR __builtin_amdgcn_s_barrier()

// lds layout (f16 elems): A bufs [0,12288) = 3 x 4096, B bufs [12288,24576)
#define GEMM_STAGE(buf, kk)                                        \
  do {                                                             \
    gl_lds16(pA0 + (kk), &lds[(buf)*4096 + wofs]);                 \
    gl_lds16(pA1 + (kk), &lds[(buf)*4096 + 2048 + wofs]);          \
    gl_lds16(pB0 + (kk), &lds[12288 + (buf)*4096 + wofs]);         \
    gl_lds16(pB1 + (kk), &lds[12288 + (buf)*4096 + 2048 + wofs]);  \
  } while (0)

#define GEMM_COMPUTE(aB, bB)                             \
  do {                                                   \
    f16x8 af0, af1, af2, af3, bf0, bf1, bf2, bf3;        \
    DSR(af0, aB, "0");                                   \
    DSR(bf0, bB, "0");                                   \
    DSR(af1, aB, "1024");                                \
    DSR(bf1, bB, "1024");                                \
    DSR(af2, aB, "2048");                                \
    DSR(bf2, bB, "2048");                                \
    DSR(af3, aB, "3072");                                \
    DSR(bf3, bB, "3072");                                \
    asm volatile("s_waitcnt lgkmcnt(4)" ::: "memory");   \
    __builtin_amdgcn_sched_barrier(0);                   \
    __builtin_amdgcn_s_setprio(1);                       \
    acc[0][0] = mfma32(af0, bf0, acc[0][0]);             \
    acc[0][1] = mfma32(af0, bf1, acc[0][1]);             \
    acc[1][0] = mfma32(af1, bf0, acc[1][0]);             \
    acc[1][1] = mfma32(af1, bf1, acc[1][1]);             \
    asm volatile("s_waitcnt lgkmcnt(0)" ::: "memory");   \
    __builtin_amdgcn_sched_barrier(0);                   \
    acc[0][2] = mfma32(af0, bf2, acc[0][2]);             \
    acc[0][3] = mfma32(af0, bf3, acc[0][3]);             \
    acc[1][2] = mfma32(af1, bf2, acc[1][2]);             \
    acc[1][3] = mfma32(af1, bf3, acc[1][3]);             \
    acc[2][0] = mfma32(af2, bf0, acc[2][0]);             \
    acc[2][1] = mfma32(af2, bf1, acc[2][1]);             \
    acc[2][2] = mfma32(af2, bf2, acc[2][2]);             \
    acc[2][3] = mfma32(af2, bf3, acc[2][3]);             \
    acc[3][0] = mfma32(af3, bf0, acc[3][0]);             \
    acc[3][1] = mfma32(af3, bf1, acc[3][1]);             \
    acc[3][2] = mfma32(af3, bf2, acc[3][2]);             \
    acc[3][3] = mfma32(af3, bf3, acc[3][3]);             \
    __builtin_amdgcn_s_setprio(0);                       \
  } while (0)

template <int MODE>
__global__ __launch_bounds__(256, 3) void gemm_kernel(
    const _Float16* __restrict__ A, const _Float16* __restrict__ Bm,
    int M, int N, int K,
    const float* __restrict__ bias_q, const float* __restrict__ bias_v,
    _Float16* __restrict__ qkbuf, _Float16* __restrict__ vtbuf,
    const float* __restrict__ bias_o, float* __restrict__ outf) {
  __shared__ __align__(16) _Float16 lds[6 * 4096];  // 48 KB, reused by epilogue
  const int t = threadIdx.x;
  const int w = t >> 6;
  const int lane = t & 63;
  const int lq = lane & 15, lg = lane >> 4;
  const int wr = w >> 1, wc = w & 1;
  const int m0 = blockIdx.y * 128, n0 = blockIdx.x * 128;

  const int stc = ((t & 3) ^ ((t >> 3) & 3)) * 8;
  const _Float16* pA0 = A + (size_t)(m0 + (t >> 2)) * K + stc;
  const _Float16* pA1 = pA0 + (size_t)64 * K;
  const _Float16* pB0 = Bm + (size_t)(n0 + (t >> 2)) * K + stc;
  const _Float16* pB1 = pB0 + (size_t)64 * K;
  const int wofs = w * 512;

  const int xsw = (lq >> 1) & 3;
  const uint32_t base = (uint32_t)(uintptr_t)(lds_f16p)&lds[0];
  const uint32_t aB0 =
      base + (uint32_t)((wr * 64 + lq) * 64 + ((lg ^ xsw) << 4));
  const uint32_t aB1 = aB0 + 8192;
  const uint32_t aB2 = aB0 + 16384;
  const uint32_t bB0 =
      base + 24576 + (uint32_t)((wc * 64 + lq) * 64 + ((lg ^ xsw) << 4));
  const uint32_t bB1 = bB0 + 8192;
  const uint32_t bB2 = bB0 + 16384;

  f32x4 acc[4][4];
#pragma unroll
  for (int mi = 0; mi < 4; ++mi)
#pragma unroll
    for (int ni = 0; ni < 4; ++ni) acc[mi][ni] = (f32x4){0.f, 0.f, 0.f, 0.f};

  GEMM_STAGE(0, 0);
  GEMM_STAGE(1, 32);
  for (int kt = 0; kt + 160 <= K; kt += 96) {
    GEMM_STAGE(2, kt + 64);
    GEMM_VM8;
    GEMM_BAR;
    GEMM_COMPUTE(aB0, bB0);
    GEMM_BAR;
    GEMM_STAGE(0, kt + 96);
    GEMM_VM8;
    GEMM_BAR;
    GEMM_COMPUTE(aB1, bB1);
    GEMM_BAR;
    GEMM_STAGE(1, kt + 128);
    GEMM_VM8;
    GEMM_BAR;
    GEMM_COMPUTE(aB2, bB2);
    GEMM_BAR;
  }
  GEMM_VM4;
  GEMM_BAR;
  GEMM_COMPUTE(aB0, bB0);
  GEMM_BAR;
  GEMM_VM0;
  GEMM_BAR;
  GEMM_COMPUTE(aB1, bB1);

  if (MODE == 0) {
    // coalesced epilogue via LDS staging tile T[128][136] (f16, 34.8 KB)
    GEMM_BAR;  // all waves done reading frag buffers; lds reusable
    _Float16* T = &lds[0];
    const bool isqk = (n0 < 2048);  // block-uniform
    const int bb = m0 >> 10, ii0 = m0 & 1023;
    if (isqk) {
#pragma unroll
      for (int mi = 0; mi < 4; ++mi)
#pragma unroll
        for (int ni = 0; ni < 4; ++ni) {
          const int col = wc * 64 + ni * 16 + lq;
          const float bq = bias_q[n0 + col];
#pragma unroll
          for (int r = 0; r < 4; ++r) {
            const int row = wr * 64 + mi * 16 + lg * 4 + r;
            T[row * 136 + col] = (_Float16)(acc[mi][ni][r] + bq);
          }
        }
      __syncthreads();
      const int hh = n0 >> 7;  // one head per 128-wide tile
      _Float16* gb = qkbuf + ((size_t)((bb * 16 + hh) * 1024 + ii0)) * 128;
      const int row = t >> 1, half = t & 1;
      const int so = row * 136 + half * 64;
      const int go = row * 128 + half * 64;
#pragma unroll
      for (int j = 0; j < 8; ++j)
        *(f16x8*)(gb + go + j * 8) = *(const f16x8*)&T[so + j * 8];
    } else {
      const int nn0 = n0 - 2048;
#pragma unroll
      for (int mi = 0; mi < 4; ++mi)
#pragma unroll
        for (int ni = 0; ni < 4; ++ni) {
          const int col = wc * 64 + ni * 16 + lq;
          const float bv = bias_v[nn0 + col];
          const int row0 = wr * 64 + mi * 16 + lg * 4;
          f16x4 p;
#pragma unroll
          for (int r = 0; r < 4; ++r) p[r] = (_Float16)(acc[mi][ni][r] + bv);
          *(f16x4*)&T[col * 136 + row0] = p;
        }
      __syncthreads();
      const int c = t >> 1, half = t & 1;
      const int nn = nn0 + c;
      const int hh = nn >> 6, dv = nn & 63;
      _Float16* gb = vtbuf + ((size_t)((bb * 16 + hh) * 64 + dv)) * 1024 +
                     ii0 + half * 64;
      const int so = c * 136 + half * 64;
#pragma unroll
      for (int j = 0; j < 8; ++j)
        *(f16x8*)(gb + j * 8) = *(const f16x8*)&T[so + j * 8];
    }
  } else {
#pragma unroll
    for (int mi = 0; mi < 4; ++mi)
#pragma unroll
      for (int ni = 0; ni < 4; ++ni)
#pragma unroll
        for (int r = 0; r < 4; ++r) {
          const int mg = m0 + wr * 64 + mi * 16 + lg * 4 + r;
          const int ng = n0 + wc * 64 + ni * 16 + lq;
          outf[(size_t)mg * N + ng] = acc[mi][ni][r] + bias_o[ng];
        }
  }
}

// ------------------------------- attention --------------------------------
// 4-wave known-good version (typed LDS reads, single __syncthreads, compiler
// scheduling). Block owns q-tile PAIR (tA=b4, tB=15-b4) of one (b,h):
// constant work per block; barrier-synced LDS staging of K/V tiles
// (KVBLK=64), double-buffered, swizzled.
__device__ __forceinline__ void stage_kv(const _Float16* __restrict__ kb,
                                         const _Float16* __restrict__ vtb,
                                         int j0, _Float16* kl, _Float16* vl,
                                         int t) {
  const int r0 = t >> 3, c0 = t & 7;
  const int r1 = r0 + 32;
  const int kc0 = c0 ^ (r0 & 7), kc1 = c0 ^ (r1 & 7);
  gl_lds16(kb + (size_t)(j0 + r0) * 128 + kc0 * 8, kl + t * 8);
  gl_lds16(kb + (size_t)(j0 + r1) * 128 + kc1 * 8, kl + (t + 256) * 8);
  gl_lds16(vtb + (size_t)r0 * 1024 + j0 + kc0 * 8, vl + t * 8);
  gl_lds16(vtb + (size_t)r1 * 1024 + j0 + kc1 * 8, vl + (t + 256) * 8);
}

__device__ __forceinline__ void softmax16(f32x4 (&st)[4], f16x4 (&ph)[4],
                                          int qi, int j0, bool far,
                                          const float* __restrict__ tab,
                                          float t128, int lg4, float& m_run,
                                          float& l_part, f32x4 (&oacc)[4]) {
  float xs[16];
  float lmax = NEG_INF;
  if (far) {
#pragma unroll
    for (int js = 0; js < 4; ++js)
#pragma unroll
      for (int r = 0; r < 4; ++r) {
        const float xv = fmaf(st[js][r], 0.125f * LOG2E, t128);
        xs[js * 4 + r] = xv;
        lmax = fmaxf(lmax, xv);
      }
  } else {
#pragma unroll
    for (int js = 0; js < 4; ++js)
#pragma unroll
      for (int r = 0; r < 4; ++r) {
        const int jj = j0 + js * 16 + lg4 + r;
        const int dd = qi - jj;
        const int idx = dd < 0 ? 0 : (dd > 128 ? 128 : dd);
        const float xv =
            (dd < 0) ? NEG_INF : fmaf(st[js][r], 0.125f * LOG2E, tab[idx]);
        xs[js * 4 + r] = xv;
        lmax = fmaxf(lmax, xv);
      }
  }
  if (__any(lmax > m_run + 8.0f)) {
    float tmax = fmaxf(lmax, __shfl_xor(lmax, 16));
    tmax = fmaxf(tmax, __shfl_xor(tmax, 32));
    const float m_new = fmaxf(m_run, tmax);
    const float sf = EXP2(m_run - m_new);
    m_run = m_new;
    l_part *= sf;
    f32x4 sfv;
#pragma unroll
    for (int r = 0; r < 4; ++r) sfv[r] = __shfl(sf, lg4 + r);
#pragma unroll
    for (int db = 0; db < 4; ++db) oacc[db] *= sfv;
  }
  float ls = 0.f;
#pragma unroll
  for (int js = 0; js < 4; ++js)
#pragma unroll
    for (int r = 0; r < 4; ++r) {
      const float p = EXP2(xs[js * 4 + r] - m_run);
      ls += p;
      ph[js][r] = (_Float16)p;
    }
  l_part += ls;
}

__global__ __launch_bounds__(256, 4) void attn_kernel(
    const _Float16* __restrict__ qk,  // [B*H][1024][128] (q | k)
    const _Float16* __restrict__ vt,  // [B*H][64][1024]  (V^T)
    const float* __restrict__ bias,   // [32][16]
    _Float16* __restrict__ ao) {      // [B][1024][H*64]
  __shared__ __align__(16) _Float16 kls[2][64 * 64];
  __shared__ __align__(16) _Float16 vls[2][64 * 64];
  __shared__ float tab[132];
  const int t = threadIdx.x;
  const int bid = blockIdx.x;
  const int bh = (bid & 7) * 16 + (bid >> 6);
  const int b4 = (bid >> 3) & 7;
  const int h = bh & 15, b = bh >> 4;
  if (t < 129) {
    const int bucket =
        (t <= 16) ? t : 16 + (int)(log((double)(t - 15)) * 15.0 / log(113.0));
    tab[t] = bias[bucket * 16 + h] * LOG2E;
  }

  const int w = t >> 6, lane = t & 63;
  const int lq = lane & 15, lg = lane >> 4;
  const int lg4 = lg * 4, lg8 = lg * 8;
  const int tA = b4, tB = 15 - b4;
  const int q0A = tA * 64 + w * 16, q0B = tB * 64 + w * 16;
  const int qA = q0A + lq, qB = q0B + lq;
  const _Float16* qkb = qk + (size_t)bh * 1024 * 128;
  const _Float16* kb = qkb + 64;
  const _Float16* vtb = vt + (size_t)bh * 64 * 1024;

  const f16x8 qfA0 = *(const f16x8*)&qkb[qA * 128 + lg8];
  const f16x8 qfA1 = *(const f16x8*)&qkb[qA * 128 + 32 + lg8];
  const f16x8 qfB0 = *(const f16x8*)&qkb[qB * 128 + lg8];
  const f16x8 qfB1 = *(const f16x8*)&qkb[qB * 128 + 32 + lg8];

  f32x4 oA[4], oB[4];
#pragma unroll
  for (int db = 0; db < 4; ++db) {
    oA[db] = (f32x4){0.f, 0.f, 0.f, 0.f};
    oB[db] = (f32x4){0.f, 0.f, 0.f, 0.f};
  }
  float mA = NEG_INF, lAp = 0.f, mB = NEG_INF, lBp = 0.f;

  stage_kv(kb, vtb, 0, kls[0], vls[0], t);
  __syncthreads();
  const float t128 = tab[128];
  const int krsw = lq & 7;
  const int vsw = (lq & 7) << 1;
  int cur = 0;

  for (int jt = 0; jt <= tB; ++jt) {
    const int j0 = jt * 64;
    if (jt < tB) stage_kv(kb, vtb, j0 + 64, kls[cur ^ 1], vls[cur ^ 1], t);
    const bool aact = (jt <= tA);
    const _Float16* kbf = kls[cur];
    const _Float16* vbf = vls[cur];

    f32x4 stA[4], stB[4];
#pragma unroll
    for (int js = 0; js < 4; ++js) {
      const int rowb = (js * 16 + lq) * 64;
      const f16x8 kf0 = *(const f16x8*)&kbf[rowb + ((lg ^ krsw) << 3)];
      const f16x8 kf1 = *(const f16x8*)&kbf[rowb + (((lg + 4) ^ krsw) << 3)];
      if (aact) {
        stA[js] = mfma32(kf0, qfA0, (f32x4){0.f, 0.f, 0.f, 0.f});
        stA[js] = mfma32(kf1, qfA1, stA[js]);
      }
      stB[js] = mfma32(kf0, qfB0, (f32x4){0.f, 0.f, 0.f, 0.f});
      stB[js] = mfma32(kf1, qfB1, stB[js]);
    }

    f16x4 phA[4], phB[4];
    if (aact)
      softmax16(stA, phA, qA, j0, q0A - j0 >= 192, tab, t128, lg4, mA, lAp,
                oA);
    softmax16(stB, phB, qB, j0, q0B - j0 >= 192, tab, t128, lg4, mB, lBp, oB);

#pragma unroll
    for (int js = 0; js < 4; ++js)
#pragma unroll
      for (int db = 0; db < 4; ++db) {
        const f16x4 vf = *(const f16x4*)&vbf[(db * 16 + lq) * 64 +
                                             ((((js << 2) + lg) ^ vsw) << 2)];
        if (aact) oA[db] = mfma16(phA[js], vf, oA[db]);
        oB[db] = mfma16(phB[js], vf, oB[db]);
      }

    __syncthreads();
    cur ^= 1;
  }

  _Float16* aob = ao + ((size_t)b * 1024) * 1024 + h * 64;
  {
    float lt = lAp + __shfl_xor(lAp, 16);
    lt += __shfl_xor(lt, 32);
    f32x4 linv;
#pragma unroll
    for (int r = 0; r < 4; ++r) linv[r] = 1.0f / __shfl(lt, lg4 + r);
#pragma unroll
    for (int db = 0; db < 4; ++db)
#pragma unroll
      for (int r = 0; r < 4; ++r)
        aob[(size_t)(q0A + lg4 + r) * 1024 + db * 16 + lq] =
            (_Float16)(oA[db][r] * linv[r]);
  }
  {
    float lt = lBp + __shfl_xor(lBp, 16);
    lt += __shfl_xor(lt, 32);
    f32x4 linv;
#pragma unroll
    for (int r = 0; r < 4; ++r) linv[r] = 1.0f / __shfl(lt, lg4 + r);
#pragma unroll
    for (int db = 0; db < 4; ++db)
#pragma unroll
      for (int r = 0; r < 4; ++r)
        aob[(size_t)(q0B + lg4 + r) * 1024 + db * 16 + lq] =
            (_Float16)(oB[db][r] * linv[r]);
  }
}

// -------------------------------- launch ----------------------------------
extern "C" void kernel_launch(void* const* d_in, const int* in_sizes, int n_in,
                              void* d_out, int out_size, void* d_ws,
                              size_t ws_size, hipStream_t stream) {
  const float* x = (const float*)d_in[0];
  const float* qk_w = (const float*)d_in[1];
  const float* qk_b = (const float*)d_in[2];
  const float* v_w = (const float*)d_in[3];
  const float* v_b = (const float*)d_in[4];
  const float* out_w = (const float*)d_in[5];
  const float* out_b = (const float*)d_in[6];
  const float* bias = (const float*)d_in[7];
  float* out = (float*)d_out;

  // workspace (fp16 elems): xb 8M | wb 3M | owb 1M | qk 16M | vt 8M | ao 8M
  _Float16* xb = (_Float16*)d_ws;
  _Float16* wb = xb + (size_t)8388608;
  _Float16* owb = wb + (size_t)3145728;
  _Float16* qkbuf = owb + (size_t)1048576;
  _Float16* vtbuf = qkbuf + (size_t)16777216;
  _Float16* ao = vtbuf + (size_t)8388608;

  // all conversions in one launch
  cvt4_kernel<<<12288, 256, 0, stream>>>(x, qk_w, v_w, out_w, xb, wb,
                                         wb + 2097152, owb);

  // fused QKV projection: M=8192, N=3072 (2048 qk | 1024 v), K=1024
  gemm_kernel<0><<<dim3(24, 64), 256, 0, stream>>>(
      xb, wb, 8192, 3072, 1024, qk_b, v_b, qkbuf, vtbuf, nullptr, nullptr);

  // flash attention: 8 balanced blocks per (b,h)
  attn_kernel<<<1024, 256, 0, stream>>>(qkbuf, vtbuf, bias, ao);

  // output projection: M=8192, N=1024, K=1024 -> fp32 d_out
  gemm_kernel<1><<<dim3(8, 64), 256, 0, stream>>>(
      ao, owb, 8192, 1024, 1024, nullptr, nullptr, nullptr, nullptr, out_b, out);
}

// Round 20
// 157.499 us; speedup vs baseline: 1.0333x; 1.0013x over previous
//
#include <hip/hip_runtime.h>
#include <cmath>

// ---------------------------------------------------------------------------
// T5 MHSA: x->(QKV proj, f16 MFMA GEMM) -> flash attn w/ T5 bias -> out proj
// All matmuls on MFMA. fp16 intermediates, fp32 accum.
// R20 = R14/R19 + attention CU-load balancing: b4 XOR-permuted by bid>>8 so
// the 4 co-resident blocks per CU have j-loop lengths summing to a constant
// (50 units/CU) instead of 4 identical lengths (36..64 spread, ~28% tail).
// ---------------------------------------------------------------------------

typedef _Float16 f16x8 __attribute__((ext_vector_type(8)));
typedef _Float16 f16x4 __attribute__((ext_vector_type(4)));
typedef float    f32x4 __attribute__((ext_vector_type(4)));

#define NEG_INF (-__builtin_inff())
#define LOG2E 1.4426950408889634f

#if __has_builtin(__builtin_amdgcn_exp2f)
#define EXP2(x) __builtin_amdgcn_exp2f(x)
#else
#define EXP2(x) exp2f(x)
#endif

__device__ __forceinline__ void gl_lds16(const void* g, void* l) {
  __builtin_amdgcn_global_load_lds(
      (__attribute__((address_space(1))) void*)g,
      (__attribute__((address_space(3))) void*)l,
      16, 0, 0);
}

__device__ __forceinline__ f32x4 mfma32(f16x8 a, f16x8 b, f32x4 c) {
  return __builtin_amdgcn_mfma_f32_16x16x32_f16(a, b, c, 0, 0, 0);
}
__device__ __forceinline__ f32x4 mfma16(f16x4 a, f16x4 b, f32x4 c) {
  return __builtin_amdgcn_mfma_f32_16x16x16f16(a, b, c, 0, 0, 0);
}

typedef __attribute__((address_space(3))) _Float16* lds_f16p;

#define DSR(d, a, o) \
  asm volatile("ds_read_b128 %0, %1 offset:" o : "=v"(d) : "v"(a))

// -------------------------------- convert ---------------------------------
// single launch for all 4 fp32->fp16 conversions (saves 3 launch gaps)
__global__ void cvt4_kernel(const float* __restrict__ x,
                            const float* __restrict__ w1,
                            const float* __restrict__ w2,
                            const float* __restrict__ w3,
                            _Float16* __restrict__ ox, _Float16* __restrict__ o1,
                            _Float16* __restrict__ o2, _Float16* __restrict__ o3) {
  const int bid = blockIdx.x;
  const float* src;
  _Float16* dst;
  int idx;
  if (bid < 8192) {
    src = x; dst = ox; idx = bid * 256 + threadIdx.x;
  } else if (bid < 10240) {
    src = w1; dst = o1; idx = (bid - 8192) * 256 + threadIdx.x;
  } else if (bid < 11264) {
    src = w2; dst = o2; idx = (bid - 10240) * 256 + threadIdx.x;
  } else {
    src = w3; dst = o3; idx = (bid - 11264) * 256 + threadIdx.x;
  }
  float4 v = reinterpret_cast<const float4*>(src)[idx];
  f16x4 o;
  o[0] = (_Float16)v.x; o[1] = (_Float16)v.y;
  o[2] = (_Float16)v.z; o[3] = (_Float16)v.w;
  reinterpret_cast<f16x4*>(dst)[idx] = o;
}

// --------------------------------- GEMM -----------------------------------
// C = A(MxK) * Bm(NxK)^T.  128x128 tile, BK=32, 4 waves (2x2 of 64x64).
// 3-deep pipeline: triple-buffer LDS; stage tile s+2 during compute of tile
// s; counted vmcnt(8) keeps 2 tiles in flight across raw s_barriers. asm
// ds_read keeps the loop waitcnt-opaque. LDS chunk-XOR swizzle keeps
// ds_read conflict-free. MODE-0 epilogue stages the C-tile through LDS
// (freed after the K-loop) so qk/v outputs are written with fully-coalesced
// wave-wide f16x8 stores instead of 64 scattered scalar fp16 stores/thread.
#define GEMM_VM8 asm volatile("s_waitcnt vmcnt(8)" ::: "memory")
#define GEMM_VM4 asm volatile("s_waitcnt vmcnt(4)" ::: "memory")
#define GEMM_VM0 asm volatile("s_waitcnt vmcnt(0)" ::: "memory")
#define GEMM_BAR __builtin_amdgcn_s_barrier()

// lds layout (f16 elems): A bufs [0,12288) = 3 x 4096, B bufs [12288,24576)
#define GEMM_STAGE(buf, kk)                                        \
  do {                                                             \
    gl_lds16(pA0 + (kk), &lds[(buf)*4096 + wofs]);                 \
    gl_lds16(pA1 + (kk), &lds[(buf)*4096 + 2048 + wofs]);          \
    gl_lds16(pB0 + (kk), &lds[12288 + (buf)*4096 + wofs]);         \
    gl_lds16(pB1 + (kk), &lds[12288 + (buf)*4096 + 2048 + wofs]);  \
  } while (0)

#define GEMM_COMPUTE(aB, bB)                             \
  do {                                                   \
    f16x8 af0, af1, af2, af3, bf0, bf1, bf2, bf3;        \
    DSR(af0, aB, "0");                                   \
    DSR(bf0, bB, "0");                                   \
    DSR(af1, aB, "1024");                                \
    DSR(bf1, bB, "1024");                                \
    DSR(af2, aB, "2048");                                \
    DSR(bf2, bB, "2048");                                \
    DSR(af3, aB, "3072");                                \
    DSR(bf3, bB, "3072");                                \
    asm volatile("s_waitcnt lgkmcnt(4)" ::: "memory");   \
    __builtin_amdgcn_sched_barrier(0);                   \
    __builtin_amdgcn_s_setprio(1);                       \
    acc[0][0] = mfma32(af0, bf0, acc[0][0]);             \
    acc[0][1] = mfma32(af0, bf1, acc[0][1]);             \
    acc[1][0] = mfma32(af1, bf0, acc[1][0]);             \
    acc[1][1] = mfma32(af1, bf1, acc[1][1]);             \
    asm volatile("s_waitcnt lgkmcnt(0)" ::: "memory");   \
    __builtin_amdgcn_sched_barrier(0);                   \
    acc[0][2] = mfma32(af0, bf2, acc[0][2]);             \
    acc[0][3] = mfma32(af0, bf3, acc[0][3]);             \
    acc[1][2] = mfma32(af1, bf2, acc[1][2]);             \
    acc[1][3] = mfma32(af1, bf3, acc[1][3]);             \
    acc[2][0] = mfma32(af2, bf0, acc[2][0]);             \
    acc[2][1] = mfma32(af2, bf1, acc[2][1]);             \
    acc[2][2] = mfma32(af2, bf2, acc[2][2]);             \
    acc[2][3] = mfma32(af2, bf3, acc[2][3]);             \
    acc[3][0] = mfma32(af3, bf0, acc[3][0]);             \
    acc[3][1] = mfma32(af3, bf1, acc[3][1]);             \
    acc[3][2] = mfma32(af3, bf2, acc[3][2]);             \
    acc[3][3] = mfma32(af3, bf3, acc[3][3]);             \
    __builtin_amdgcn_s_setprio(0);                       \
  } while (0)

template <int MODE>
__global__ __launch_bounds__(256, 3) void gemm_kernel(
    const _Float16* __restrict__ A, const _Float16* __restrict__ Bm,
    int M, int N, int K,
    const float* __restrict__ bias_q, const float* __restrict__ bias_v,
    _Float16* __restrict__ qkbuf, _Float16* __restrict__ vtbuf,
    const float* __restrict__ bias_o, float* __restrict__ outf) {
  __shared__ __align__(16) _Float16 lds[6 * 4096];  // 48 KB, reused by epilogue
  const int t = threadIdx.x;
  const int w = t >> 6;
  const int lane = t & 63;
  const int lq = lane & 15, lg = lane >> 4;
  const int wr = w >> 1, wc = w & 1;
  const int m0 = blockIdx.y * 128, n0 = blockIdx.x * 128;

  const int stc = ((t & 3) ^ ((t >> 3) & 3)) * 8;
  const _Float16* pA0 = A + (size_t)(m0 + (t >> 2)) * K + stc;
  const _Float16* pA1 = pA0 + (size_t)64 * K;
  const _Float16* pB0 = Bm + (size_t)(n0 + (t >> 2)) * K + stc;
  const _Float16* pB1 = pB0 + (size_t)64 * K;
  const int wofs = w * 512;

  const int xsw = (lq >> 1) & 3;
  const uint32_t base = (uint32_t)(uintptr_t)(lds_f16p)&lds[0];
  const uint32_t aB0 =
      base + (uint32_t)((wr * 64 + lq) * 64 + ((lg ^ xsw) << 4));
  const uint32_t aB1 = aB0 + 8192;
  const uint32_t aB2 = aB0 + 16384;
  const uint32_t bB0 =
      base + 24576 + (uint32_t)((wc * 64 + lq) * 64 + ((lg ^ xsw) << 4));
  const uint32_t bB1 = bB0 + 8192;
  const uint32_t bB2 = bB0 + 16384;

  f32x4 acc[4][4];
#pragma unroll
  for (int mi = 0; mi < 4; ++mi)
#pragma unroll
    for (int ni = 0; ni < 4; ++ni) acc[mi][ni] = (f32x4){0.f, 0.f, 0.f, 0.f};

  GEMM_STAGE(0, 0);
  GEMM_STAGE(1, 32);
  for (int kt = 0; kt + 160 <= K; kt += 96) {
    GEMM_STAGE(2, kt + 64);
    GEMM_VM8;
    GEMM_BAR;
    GEMM_COMPUTE(aB0, bB0);
    GEMM_BAR;
    GEMM_STAGE(0, kt + 96);
    GEMM_VM8;
    GEMM_BAR;
    GEMM_COMPUTE(aB1, bB1);
    GEMM_BAR;
    GEMM_STAGE(1, kt + 128);
    GEMM_VM8;
    GEMM_BAR;
    GEMM_COMPUTE(aB2, bB2);
    GEMM_BAR;
  }
  GEMM_VM4;
  GEMM_BAR;
  GEMM_COMPUTE(aB0, bB0);
  GEMM_BAR;
  GEMM_VM0;
  GEMM_BAR;
  GEMM_COMPUTE(aB1, bB1);

  if (MODE == 0) {
    // coalesced epilogue via LDS staging tile T[128][136] (f16, 34.8 KB)
    GEMM_BAR;  // all waves done reading frag buffers; lds reusable
    _Float16* T = &lds[0];
    const bool isqk = (n0 < 2048);  // block-uniform
    const int bb = m0 >> 10, ii0 = m0 & 1023;
    if (isqk) {
#pragma unroll
      for (int mi = 0; mi < 4; ++mi)
#pragma unroll
        for (int ni = 0; ni < 4; ++ni) {
          const int col = wc * 64 + ni * 16 + lq;
          const float bq = bias_q[n0 + col];
#pragma unroll
          for (int r = 0; r < 4; ++r) {
            const int row = wr * 64 + mi * 16 + lg * 4 + r;
            T[row * 136 + col] = (_Float16)(acc[mi][ni][r] + bq);
          }
        }
      __syncthreads();
      const int hh = n0 >> 7;  // one head per 128-wide tile
      _Float16* gb = qkbuf + ((size_t)((bb * 16 + hh) * 1024 + ii0)) * 128;
      const int row = t >> 1, half = t & 1;
      const int so = row * 136 + half * 64;
      const int go = row * 128 + half * 64;
#pragma unroll
      for (int j = 0; j < 8; ++j)
        *(f16x8*)(gb + go + j * 8) = *(const f16x8*)&T[so + j * 8];
    } else {
      const int nn0 = n0 - 2048;
#pragma unroll
      for (int mi = 0; mi < 4; ++mi)
#pragma unroll
        for (int ni = 0; ni < 4; ++ni) {
          const int col = wc * 64 + ni * 16 + lq;
          const float bv = bias_v[nn0 + col];
          const int row0 = wr * 64 + mi * 16 + lg * 4;
          f16x4 p;
#pragma unroll
          for (int r = 0; r < 4; ++r) p[r] = (_Float16)(acc[mi][ni][r] + bv);
          *(f16x4*)&T[col * 136 + row0] = p;
        }
      __syncthreads();
      const int c = t >> 1, half = t & 1;
      const int nn = nn0 + c;
      const int hh = nn >> 6, dv = nn & 63;
      _Float16* gb = vtbuf + ((size_t)((bb * 16 + hh) * 64 + dv)) * 1024 +
                     ii0 + half * 64;
      const int so = c * 136 + half * 64;
#pragma unroll
      for (int j = 0; j < 8; ++j)
        *(f16x8*)(gb + j * 8) = *(const f16x8*)&T[so + j * 8];
    }
  } else {
#pragma unroll
    for (int mi = 0; mi < 4; ++mi)
#pragma unroll
      for (int ni = 0; ni < 4; ++ni)
#pragma unroll
        for (int r = 0; r < 4; ++r) {
          const int mg = m0 + wr * 64 + mi * 16 + lg * 4 + r;
          const int ng = n0 + wc * 64 + ni * 16 + lq;
          outf[(size_t)mg * N + ng] = acc[mi][ni][r] + bias_o[ng];
        }
  }
}

// ------------------------------- attention --------------------------------
// 4-wave known-good version + CU-load balancing. Block owns q-tile PAIR
// (tA=b4, tB=15-b4) of one (b,h). b4 is XOR-permuted by (bid>>8)&3 with
// xv={0,7,1,6}: co-resident blocks on a CU (bids differing by 256 under
// round-robin dispatch) get j-loop lengths {16-v, 16-(v^7), 16-(v^1),
// 16-(v^6)} whose sum is 50 for every v -> uniform CU load instead of 4
// identical lengths (36..64 spread). XOR is bijective per (b,h): coverage
// and per-block work unchanged.
__device__ __forceinline__ void stage_kv(const _Float16* __restrict__ kb,
                                         const _Float16* __restrict__ vtb,
                                         int j0, _Float16* kl, _Float16* vl,
                                         int t) {
  const int r0 = t >> 3, c0 = t & 7;
  const int r1 = r0 + 32;
  const int kc0 = c0 ^ (r0 & 7), kc1 = c0 ^ (r1 & 7);
  gl_lds16(kb + (size_t)(j0 + r0) * 128 + kc0 * 8, kl + t * 8);
  gl_lds16(kb + (size_t)(j0 + r1) * 128 + kc1 * 8, kl + (t + 256) * 8);
  gl_lds16(vtb + (size_t)r0 * 1024 + j0 + kc0 * 8, vl + t * 8);
  gl_lds16(vtb + (size_t)r1 * 1024 + j0 + kc1 * 8, vl + (t + 256) * 8);
}

__device__ __forceinline__ void softmax16(f32x4 (&st)[4], f16x4 (&ph)[4],
                                          int qi, int j0, bool far,
                                          const float* __restrict__ tab,
                                          float t128, int lg4, float& m_run,
                                          float& l_part, f32x4 (&oacc)[4]) {
  float xs[16];
  float lmax = NEG_INF;
  if (far) {
#pragma unroll
    for (int js = 0; js < 4; ++js)
#pragma unroll
      for (int r = 0; r < 4; ++r) {
        const float xv = fmaf(st[js][r], 0.125f * LOG2E, t128);
        xs[js * 4 + r] = xv;
        lmax = fmaxf(lmax, xv);
      }
  } else {
#pragma unroll
    for (int js = 0; js < 4; ++js)
#pragma unroll
      for (int r = 0; r < 4; ++r) {
        const int jj = j0 + js * 16 + lg4 + r;
        const int dd = qi - jj;
        const int idx = dd < 0 ? 0 : (dd > 128 ? 128 : dd);
        const float xv =
            (dd < 0) ? NEG_INF : fmaf(st[js][r], 0.125f * LOG2E, tab[idx]);
        xs[js * 4 + r] = xv;
        lmax = fmaxf(lmax, xv);
      }
  }
  if (__any(lmax > m_run + 8.0f)) {
    float tmax = fmaxf(lmax, __shfl_xor(lmax, 16));
    tmax = fmaxf(tmax, __shfl_xor(tmax, 32));
    const float m_new = fmaxf(m_run, tmax);
    const float sf = EXP2(m_run - m_new);
    m_run = m_new;
    l_part *= sf;
    f32x4 sfv;
#pragma unroll
    for (int r = 0; r < 4; ++r) sfv[r] = __shfl(sf, lg4 + r);
#pragma unroll
    for (int db = 0; db < 4; ++db) oacc[db] *= sfv;
  }
  float ls = 0.f;
#pragma unroll
  for (int js = 0; js < 4; ++js)
#pragma unroll
    for (int r = 0; r < 4; ++r) {
      const float p = EXP2(xs[js * 4 + r] - m_run);
      ls += p;
      ph[js][r] = (_Float16)p;
    }
  l_part += ls;
}

__global__ __launch_bounds__(256, 4) void attn_kernel(
    const _Float16* __restrict__ qk,  // [B*H][1024][128] (q | k)
    const _Float16* __restrict__ vt,  // [B*H][64][1024]  (V^T)
    const float* __restrict__ bias,   // [32][16]
    _Float16* __restrict__ ao) {      // [B][1024][H*64]
  __shared__ __align__(16) _Float16 kls[2][64 * 64];
  __shared__ __align__(16) _Float16 vls[2][64 * 64];
  __shared__ float tab[132];
  const int t = threadIdx.x;
  const int bid = blockIdx.x;
  const int bh = (bid & 7) * 16 + (bid >> 6);
  // CU load balance: lengths of the 4 co-resident blocks (bid +256k) sum
  // to a constant. xv[m] = {0,7,1,6} packed in 0xC78.
  const int xv = (0xC78 >> (((bid >> 8) & 3) * 3)) & 7;
  const int b4 = ((bid >> 3) & 7) ^ xv;
  const int h = bh & 15, b = bh >> 4;
  if (t < 129) {
    const int bucket =
        (t <= 16) ? t : 16 + (int)(log((double)(t - 15)) * 15.0 / log(113.0));
    tab[t] = bias[bucket * 16 + h] * LOG2E;
  }

  const int w = t >> 6, lane = t & 63;
  const int lq = lane & 15, lg = lane >> 4;
  const int lg4 = lg * 4, lg8 = lg * 8;
  const int tA = b4, tB = 15 - b4;
  const int q0A = tA * 64 + w * 16, q0B = tB * 64 + w * 16;
  const int qA = q0A + lq, qB = q0B + lq;
  const _Float16* qkb = qk + (size_t)bh * 1024 * 128;
  const _Float16* kb = qkb + 64;
  const _Float16* vtb = vt + (size_t)bh * 64 * 1024;

  const f16x8 qfA0 = *(const f16x8*)&qkb[qA * 128 + lg8];
  const f16x8 qfA1 = *(const f16x8*)&qkb[qA * 128 + 32 + lg8];
  const f16x8 qfB0 = *(const f16x8*)&qkb[qB * 128 + lg8];
  const f16x8 qfB1 = *(const f16x8*)&qkb[qB * 128 + 32 + lg8];

  f32x4 oA[4], oB[4];
#pragma unroll
  for (int db = 0; db < 4; ++db) {
    oA[db] = (f32x4){0.f, 0.f, 0.f, 0.f};
    oB[db] = (f32x4){0.f, 0.f, 0.f, 0.f};
  }
  float mA = NEG_INF, lAp = 0.f, mB = NEG_INF, lBp = 0.f;

  stage_kv(kb, vtb, 0, kls[0], vls[0], t);
  __syncthreads();
  const float t128 = tab[128];
  const int krsw = lq & 7;
  const int vsw = (lq & 7) << 1;
  int cur = 0;

  for (int jt = 0; jt <= tB; ++jt) {
    const int j0 = jt * 64;
    if (jt < tB) stage_kv(kb, vtb, j0 + 64, kls[cur ^ 1], vls[cur ^ 1], t);
    const bool aact = (jt <= tA);
    const _Float16* kbf = kls[cur];
    const _Float16* vbf = vls[cur];

    f32x4 stA[4], stB[4];
#pragma unroll
    for (int js = 0; js < 4; ++js) {
      const int rowb = (js * 16 + lq) * 64;
      const f16x8 kf0 = *(const f16x8*)&kbf[rowb + ((lg ^ krsw) << 3)];
      const f16x8 kf1 = *(const f16x8*)&kbf[rowb + (((lg + 4) ^ krsw) << 3)];
      if (aact) {
        stA[js] = mfma32(kf0, qfA0, (f32x4){0.f, 0.f, 0.f, 0.f});
        stA[js] = mfma32(kf1, qfA1, stA[js]);
      }
      stB[js] = mfma32(kf0, qfB0, (f32x4){0.f, 0.f, 0.f, 0.f});
      stB[js] = mfma32(kf1, qfB1, stB[js]);
    }

    f16x4 phA[4], phB[4];
    if (aact)
      softmax16(stA, phA, qA, j0, q0A - j0 >= 192, tab, t128, lg4, mA, lAp,
                oA);
    softmax16(stB, phB, qB, j0, q0B - j0 >= 192, tab, t128, lg4, mB, lBp, oB);

#pragma unroll
    for (int js = 0; js < 4; ++js)
#pragma unroll
      for (int db = 0; db < 4; ++db) {
        const f16x4 vf = *(const f16x4*)&vbf[(db * 16 + lq) * 64 +
                                             ((((js << 2) + lg) ^ vsw) << 2)];
        if (aact) oA[db] = mfma16(phA[js], vf, oA[db]);
        oB[db] = mfma16(phB[js], vf, oB[db]);
      }

    __syncthreads();
    cur ^= 1;
  }

  _Float16* aob = ao + ((size_t)b * 1024) * 1024 + h * 64;
  {
    float lt = lAp + __shfl_xor(lAp, 16);
    lt += __shfl_xor(lt, 32);
    f32x4 linv;
#pragma unroll
    for (int r = 0; r < 4; ++r) linv[r] = 1.0f / __shfl(lt, lg4 + r);
#pragma unroll
    for (int db = 0; db < 4; ++db)
#pragma unroll
      for (int r = 0; r < 4; ++r)
        aob[(size_t)(q0A + lg4 + r) * 1024 + db * 16 + lq] =
            (_Float16)(oA[db][r] * linv[r]);
  }
  {
    float lt = lBp + __shfl_xor(lBp, 16);
    lt += __shfl_xor(lt, 32);
    f32x4 linv;
#pragma unroll
    for (int r = 0; r < 4; ++r) linv[r] = 1.0f / __shfl(lt, lg4 + r);
#pragma unroll
    for (int db = 0; db < 4; ++db)
#pragma unroll
      for (int r = 0; r < 4; ++r)
        aob[(size_t)(q0B + lg4 + r) * 1024 + db * 16 + lq] =
            (_Float16)(oB[db][r] * linv[r]);
  }
}

// -------------------------------- launch ----------------------------------
extern "C" void kernel_launch(void* const* d_in, const int* in_sizes, int n_in,
                              void* d_out, int out_size, void* d_ws,
                              size_t ws_size, hipStream_t stream) {
  const float* x = (const float*)d_in[0];
  const float* qk_w = (const float*)d_in[1];
  const float* qk_b = (const float*)d_in[2];
  const float* v_w = (const float*)d_in[3];
  const float* v_b = (const float*)d_in[4];
  const float* out_w = (const float*)d_in[5];
  const float* out_b = (const float*)d_in[6];
  const float* bias = (const float*)d_in[7];
  float* out = (float*)d_out;

  // workspace (fp16 elems): xb 8M | wb 3M | owb 1M | qk 16M | vt 8M | ao 8M
  _Float16* xb = (_Float16*)d_ws;
  _Float16* wb = xb + (size_t)8388608;
  _Float16* owb = wb + (size_t)3145728;
  _Float16* qkbuf = owb + (size_t)1048576;
  _Float16* vtbuf = qkbuf + (size_t)16777216;
  _Float16* ao = vtbuf + (size_t)8388608;

  // all conversions in one launch
  cvt4_kernel<<<12288, 256, 0, stream>>>(x, qk_w, v_w, out_w, xb, wb,
                                         wb + 2097152, owb);

  // fused QKV projection: M=8192, N=3072 (2048 qk | 1024 v), K=1024
  gemm_kernel<0><<<dim3(24, 64), 256, 0, stream>>>(
      xb, wb, 8192, 3072, 1024, qk_b, v_b, qkbuf, vtbuf, nullptr, nullptr);

  // flash attention: 8 balanced blocks per (b,h), CU-load-balanced lengths
  attn_kernel<<<1024, 256, 0, stream>>>(qkbuf, vtbuf, bias, ao);

  // output projection: M=8192, N=1024, K=1024 -> fp32 d_out
  gemm_kernel<1><<<dim3(8, 64), 256, 0, stream>>>(
      ao, owb, 8192, 1024, 1024, nullptr, nullptr, nullptr, nullptr, out_b, out);
}